// Round 3
// baseline (406.445 us; speedup 1.0000x reference)
//
#include <hip/hip_runtime.h>
#include <hip/hip_bf16.h>

// GATNet v11: head-partitioned, XCD-pinned layer-1 aggregation.
// v9/v10 showed k_agg1 is memory-SYSTEM bound: FETCH_SIZE 220MB vs 25.6MB
// table (random 512B gathers miss per-XCD 4MB L2 ~50%). Fix: split the
// gather by head (8 x 32 cols); store h1 head-major hH[8][n][32] so head g's
// table is 3.2MB (fits one XCD L2); persistent grid of 2048 blocks with
// g = blockIdx.x & 7 pins head g to XCD g (round-robin dispatch), making
// the gather L2-resident. als/ald layer1 become head-major [8][n].

#define LRELU(x) ((x) > 0.f ? (x) : 0.2f * (x))

typedef __attribute__((ext_vector_type(8))) short short8;
typedef __attribute__((ext_vector_type(8))) unsigned short ushort8;
typedef __attribute__((ext_vector_type(4))) float f32x4;

__device__ inline unsigned short f2b(float f) {
    __hip_bfloat16 h = __float2bfloat16(f);
    return *reinterpret_cast<unsigned short*>(&h);
}
__device__ inline float b2f(unsigned short u) {
    __hip_bfloat16 h;
    *reinterpret_cast<unsigned short*>(&h) = u;
    return __bfloat162float(h);
}
__device__ inline float bl(unsigned int u) { return __uint_as_float(u << 16); }
__device__ inline float bh(unsigned int u) { return __uint_as_float(u & 0xffff0000u); }

// ---------------- CSR build ----------------

__global__ void k_hist(const int* __restrict__ dst, int* deg, int E) {
    int i = blockIdx.x * blockDim.x + threadIdx.x;
    if (i < E) atomicAdd(&deg[dst[i]], 1);
}

__global__ __launch_bounds__(256) void k_scanA(const int* __restrict__ deg,
                                               int* __restrict__ tmp,
                                               int* __restrict__ blocksum, int n) {
    __shared__ int sc[256];
    int b = blockIdx.x, t = threadIdx.x;
    int i = b * 256 + t;
    int v = (i < n) ? deg[i] + 1 : 0;   // +1: self loop
    sc[t] = v;
    __syncthreads();
    for (int off = 1; off < 256; off <<= 1) {
        int x = 0;
        if (t >= off) x = sc[t - off];
        __syncthreads();
        sc[t] += x;
        __syncthreads();
    }
    if (i < n) tmp[i] = sc[t] - v;
    if (t == 255) blocksum[b] = sc[255];
}

__global__ __launch_bounds__(256) void k_scanB(const int* __restrict__ blocksum,
                                               int* __restrict__ blockpre, int nb) {
    __shared__ int sc[256];
    int t = threadIdx.x;
    int v = (t < nb) ? blocksum[t] : 0;
    sc[t] = v;
    __syncthreads();
    for (int off = 1; off < 256; off <<= 1) {
        int x = 0;
        if (t >= off) x = sc[t - off];
        __syncthreads();
        sc[t] += x;
        __syncthreads();
    }
    if (t < nb) blockpre[t] = sc[t] - v;
}

__global__ __launch_bounds__(256) void k_scanC(const int* __restrict__ tmp,
                                               const int* __restrict__ blockpre,
                                               int* __restrict__ offs,
                                               int* __restrict__ cursor, int n, int P) {
    int b = blockIdx.x, t = threadIdx.x;
    int i = b * 256 + t;
    if (i < n) {
        int o = tmp[i] + blockpre[b];
        offs[i] = o;
        cursor[i] = o;
    }
    if (i == 0) offs[n] = P;
}

__global__ void k_scatter(const int* __restrict__ src, const int* __restrict__ dst,
                          int* cursor, int* __restrict__ csr, int E, int n) {
    int i = blockIdx.x * blockDim.x + threadIdx.x;
    int s, d;
    if (i < E) {
        s = src[i];
        d = dst[i];
    } else if (i < E + n) {
        s = i - E;
        d = s;
    } else {
        return;
    }
    int p = atomicAdd(&cursor[d], 1);
    csr[p] = s;
}

// ---------------- weight prep: W1t[256][256], W2t[16][256] bf16 (merged) ----

__global__ __launch_bounds__(256) void k_prepw(const float* __restrict__ W1,
                                               const float* __restrict__ W2,
                                               unsigned short* __restrict__ W1t,
                                               unsigned short* __restrict__ W2t) {
    int b = blockIdx.x;
    if (b < 256) {
        int k = b, nn = threadIdx.x;
        W1t[nn * 256 + k] = f2b(W1[k * 256 + nn]);
    } else {
        int nn = b - 256, k = threadIdx.x;
        W2t[nn * 256 + k] = f2b(W2[k * 16 + nn]);
    }
}

// ---------------- GEMM1 (MFMA bf16): hH[8][n][32] = bf16(A @ W1), head-major

__global__ __launch_bounds__(256) void k_gemm1(const float* __restrict__ A,
                                               const unsigned short* __restrict__ Wt,
                                               unsigned short* __restrict__ hH, int M) {
    __shared__ unsigned short As[128][40];
    __shared__ unsigned short Bs[128][40];
    int t = threadIdx.x;
    int r0 = blockIdx.x * 128, c0 = blockIdx.y * 128;
    int srow = t >> 1, shalf = t & 1;
    int lane = t & 63, w = t >> 6;
    int lane15 = lane & 15, quad = lane >> 4;
    int rbw = (w & 1) * 64, cbw = (w >> 1) * 64;

    f32x4 acc[4][4];
#pragma unroll
    for (int i = 0; i < 4; i++)
#pragma unroll
        for (int j = 0; j < 4; j++) acc[i][j] = (f32x4)0.f;

    for (int k0 = 0; k0 < 256; k0 += 32) {
        {
            int row = r0 + srow;
            ushort8 p0, p1;
            if (row < M) {
                const float4* sp = (const float4*)&A[(size_t)row * 256 + k0 + shalf * 16];
                float4 f0 = sp[0], f1 = sp[1], f2 = sp[2], f3 = sp[3];
                p0[0] = f2b(f0.x); p0[1] = f2b(f0.y); p0[2] = f2b(f0.z); p0[3] = f2b(f0.w);
                p0[4] = f2b(f1.x); p0[5] = f2b(f1.y); p0[6] = f2b(f1.z); p0[7] = f2b(f1.w);
                p1[0] = f2b(f2.x); p1[1] = f2b(f2.y); p1[2] = f2b(f2.z); p1[3] = f2b(f2.w);
                p1[4] = f2b(f3.x); p1[5] = f2b(f3.y); p1[6] = f2b(f3.z); p1[7] = f2b(f3.w);
            } else {
                p0 = (ushort8)0; p1 = (ushort8)0;
            }
            *(ushort8*)&As[srow][shalf * 16] = p0;
            *(ushort8*)&As[srow][shalf * 16 + 8] = p1;
            const ushort8* bp = (const ushort8*)&Wt[(size_t)(c0 + srow) * 256 + k0 + shalf * 16];
            *(ushort8*)&Bs[srow][shalf * 16] = bp[0];
            *(ushort8*)&Bs[srow][shalf * 16 + 8] = bp[1];
        }
        __syncthreads();
        short8 af[4], bf[4];
#pragma unroll
        for (int i = 0; i < 4; i++)
            af[i] = *(const short8*)&As[rbw + i * 16 + lane15][quad * 8];
#pragma unroll
        for (int j = 0; j < 4; j++)
            bf[j] = *(const short8*)&Bs[cbw + j * 16 + lane15][quad * 8];
#pragma unroll
        for (int i = 0; i < 4; i++)
#pragma unroll
            for (int j = 0; j < 4; j++)
                acc[i][j] = __builtin_amdgcn_mfma_f32_16x16x32_bf16(af[i], bf[j], acc[i][j], 0, 0, 0);
        __syncthreads();
    }
#pragma unroll
    for (int i = 0; i < 4; i++) {
        int rowb = r0 + rbw + i * 16 + quad * 4;
#pragma unroll
        for (int j = 0; j < 4; j++) {
            int col = c0 + cbw + j * 16 + lane15;
            size_t hb = (size_t)(col >> 5) * M * 32 + (col & 31);
#pragma unroll
            for (int r = 0; r < 4; r++) {
                int row = rowb + r;
                if (row < M) hH[hb + (size_t)row * 32] = f2b(acc[i][j][r]);
            }
        }
    }
}

// ---------------- attention logits layer 1 (head-major in & out) -----------

__global__ __launch_bounds__(256) void k_al1(const unsigned short* __restrict__ hH,
                                             const float* __restrict__ asrc,
                                             const float* __restrict__ adst,
                                             float* __restrict__ als_t,
                                             float* __restrict__ ald_t, int n) {
    int v = blockIdx.x * 4 + (threadIdx.x >> 6);
    if (v >= n) return;
    int lane = threadIdx.x & 63;
    int head = lane >> 3, p = lane & 7;
    const uint2* hp = (const uint2*)(hH + (size_t)head * n * 32 + (size_t)v * 32);
    uint2 pk = hp[p];
    float f0 = bl(pk.x);
    float f1 = bh(pk.x);
    float f2 = bl(pk.y);
    float f3 = bh(pk.y);
    float4 a_s = ((const float4*)asrc)[lane];
    float4 a_d = ((const float4*)adst)[lane];
    float ps = f0 * a_s.x + f1 * a_s.y + f2 * a_s.z + f3 * a_s.w;
    float pd = f0 * a_d.x + f1 * a_d.y + f2 * a_d.z + f3 * a_d.w;
#pragma unroll
    for (int off = 1; off < 8; off <<= 1) {
        ps += __shfl_xor(ps, off, 64);
        pd += __shfl_xor(pd, off, 64);
    }
    if (p == 0) {
        als_t[(size_t)head * n + v] = ps;
        ald_t[(size_t)head * n + v] = pd;
    }
}

// ---------------- layer-1 aggregate: head-split, XCD-pinned, L2-resident ---
// Persistent grid: 2048 blocks (8/CU, all co-resident). Block b: head
// g = b&7 (round-robin dispatch => XCD g), node stream = b>>3. Per wave:
// one node; 64 lanes = 8 edge-slots x 8 col-pairs (uint2 = 4 cols, 8B).
// Head g's table hH[g] = 3.2MB -> resident in XCD g's 4MB L2.

__global__ __launch_bounds__(256) void k_agg1(const int* __restrict__ csr,
                                              const int* __restrict__ offs,
                                              const float* __restrict__ als_t,
                                              const float* __restrict__ ald_t,
                                              const unsigned short* __restrict__ hH,
                                              const float* __restrict__ b1,
                                              unsigned short* __restrict__ x2b, int n) {
    int wid = threadIdx.x >> 6;
    int lane = threadIdx.x & 63;
    int g = blockIdx.x & 7;
    int stream = blockIdx.x >> 3;   // 0..255
    __shared__ int su_s[4][32];
    __shared__ float ws_s[4][32];
    int* su = su_s[wid];
    float* ws = ws_s[wid];
    int slot = lane >> 3;           // 8 edge slots
    int cp = lane & 7;              // col-pair (uint2 = 4 cols)
    const float* alsg = als_t + (size_t)g * n;
    const float* aldg = ald_t + (size_t)g * n;
    const unsigned short* hg = hH + (size_t)g * n * 32;
    float4 bb = ((const float4*)b1)[g * 8 + cp];
    for (int v = stream * 4 + wid; v < n; v += 1024) {
        int start = offs[v];
        int deg = offs[v + 1] - start;
        float aldv = aldg[v];
        float a0 = 0.f, a1 = 0.f, a2 = 0.f, a3 = 0.f, wsum = 0.f;
        for (int base = 0; base < deg; base += 32) {
            int cnt = min(32, deg - base);
            int cnt8 = (cnt + 7) & ~7;
            __builtin_amdgcn_wave_barrier();
            if (lane < 32) {
                int u = v;
                float wv = 0.f;
                if (lane < cnt) {
                    u = __builtin_nontemporal_load(&csr[start + base + lane]);
                    wv = __expf(LRELU(alsg[u] + aldv));
                }
                su[lane] = u;
                ws[lane] = wv;
            }
            __builtin_amdgcn_wave_barrier();
            asm volatile("s_waitcnt lgkmcnt(0)" ::: "memory");
            __builtin_amdgcn_wave_barrier();
            for (int e = 0; e < cnt8; e += 8) {
                int u = su[e + slot];
                float wv = ws[e + slot];
                uint2 pk = ((const uint2*)(hg + (size_t)u * 32))[cp];
                a0 += wv * bl(pk.x);
                a1 += wv * bh(pk.x);
                a2 += wv * bl(pk.y);
                a3 += wv * bh(pk.y);
                wsum += wv;
            }
            __builtin_amdgcn_wave_barrier();
        }
        // reduce over 8 edge slots (lane bits 3,4,5)
#pragma unroll
        for (int off = 8; off < 64; off <<= 1) {
            a0 += __shfl_xor(a0, off, 64);
            a1 += __shfl_xor(a1, off, 64);
            a2 += __shfl_xor(a2, off, 64);
            a3 += __shfl_xor(a3, off, 64);
            wsum += __shfl_xor(wsum, off, 64);
        }
        if (slot == 0) {
            float inv = 1.0f / wsum;
            float o0 = fmaxf(a0 * inv + bb.x, 0.f);
            float o1 = fmaxf(a1 * inv + bb.y, 0.f);
            float o2 = fmaxf(a2 * inv + bb.z, 0.f);
            float o3 = fmaxf(a3 * inv + bb.w, 0.f);
            uint2 o;
            o.x = (unsigned int)f2b(o0) | ((unsigned int)f2b(o1) << 16);
            o.y = (unsigned int)f2b(o2) | ((unsigned int)f2b(o3) << 16);
            ((uint2*)(x2b + (size_t)v * 256 + g * 32))[cp] = o;
        }
    }
}

// ---------------- GEMM2 (MFMA) + fused layer-2 logits ----------------------

__global__ __launch_bounds__(256) void k_gemm2(const unsigned short* __restrict__ Xb,
                                               const unsigned short* __restrict__ W2t,
                                               const float* __restrict__ asrc,
                                               const float* __restrict__ adst,
                                               unsigned short* __restrict__ h2b,
                                               float* __restrict__ als,
                                               float* __restrict__ ald, int n) {
    int t = threadIdx.x;
    int lane = t & 63, w = t >> 6;
    int lane15 = lane & 15, quad = lane >> 4;
    int row0 = blockIdx.x * 64 + w * 16;
    f32x4 acc = (f32x4)0.f;
#pragma unroll
    for (int k0 = 0; k0 < 256; k0 += 32) {
        short8 a = *(const short8*)&Xb[(size_t)(row0 + lane15) * 256 + k0 + quad * 8];
        short8 b = *(const short8*)&W2t[lane15 * 256 + k0 + quad * 8];
        acc = __builtin_amdgcn_mfma_f32_16x16x32_bf16(a, b, acc, 0, 0, 0);
    }
    float asv = asrc[lane15], adv = adst[lane15];
#pragma unroll
    for (int r = 0; r < 4; r++) {
        int row = row0 + quad * 4 + r;
        float hv = acc[r];
        float ps = hv * asv, pd = hv * adv;
#pragma unroll
        for (int off = 1; off < 16; off <<= 1) {
            ps += __shfl_xor(ps, off, 16);
            pd += __shfl_xor(pd, off, 16);
        }
        if (row < n) {
            h2b[(size_t)row * 16 + lane15] = f2b(hv);
            if (lane15 == 0) {
                als[row] = ps;
                ald[row] = pd;
            }
        }
    }
}

// ---------------- layer-2 aggregate: wave per node + log_softmax ------------

__global__ __launch_bounds__(256) void k_agg2(const int* __restrict__ csr,
                                              const int* __restrict__ offs,
                                              const float* __restrict__ als,
                                              const float* __restrict__ aldg,
                                              const unsigned short* __restrict__ h2b,
                                              const float* __restrict__ b2,
                                              float* __restrict__ out, int n) {
    int wid = threadIdx.x >> 6;
    int v = blockIdx.x * 4 + wid;
    if (v >= n) return;
    int lane = threadIdx.x & 63;
    int start = offs[v];
    int deg = offs[v + 1] - start;
    __shared__ int su_s[4][32];
    __shared__ float ws_s[4][32];
    int* su = su_s[wid];
    float* ws = ws_s[wid];
    float aldv = aldg[v];
    int e16 = lane >> 2, cq = lane & 3;
    float a0 = 0.f, a1 = 0.f, a2 = 0.f, a3 = 0.f, wsum = 0.f;
    for (int base = 0; base < deg; base += 32) {
        int cnt = min(32, deg - base);
        int cnt16 = (cnt + 15) & ~15;
        __builtin_amdgcn_wave_barrier();
        if (lane < 32) {
            int u = v;
            float wv = 0.f;
            if (lane < cnt) {
                u = csr[start + base + lane];
                float x = als[u] + aldv;
                wv = __expf(LRELU(x));
            }
            su[lane] = u;
            ws[lane] = wv;
        }
        __builtin_amdgcn_wave_barrier();
        asm volatile("s_waitcnt lgkmcnt(0)" ::: "memory");
        __builtin_amdgcn_wave_barrier();
        for (int e = 0; e < cnt16; e += 16) {
            int u = su[e + e16];
            float wv = ws[e + e16];
            uint2 pk = ((const uint2*)(h2b + (size_t)u * 16))[cq];
            a0 += wv * bl(pk.x); a1 += wv * bh(pk.x);
            a2 += wv * bl(pk.y); a3 += wv * bh(pk.y);
            wsum += wv;
        }
        __builtin_amdgcn_wave_barrier();
    }
    // reduce over 16 edge slots (lane bits 2..5)
#pragma unroll
    for (int off = 4; off < 64; off <<= 1) {
        a0 += __shfl_xor(a0, off, 64);
        a1 += __shfl_xor(a1, off, 64);
        a2 += __shfl_xor(a2, off, 64);
        a3 += __shfl_xor(a3, off, 64);
        wsum += __shfl_xor(wsum, off, 64);
    }
    float inv = 1.0f / wsum;
    float4 bb = ((const float4*)b2)[cq];
    float o0 = a0 * inv + bb.x;
    float o1 = a1 * inv + bb.y;
    float o2 = a2 * inv + bb.z;
    float o3 = a3 * inv + bb.w;
    // log_softmax over 16 cols held as 4 lanes (cq) x 4 cols
    float mx = fmaxf(fmaxf(o0, o1), fmaxf(o2, o3));
    mx = fmaxf(mx, __shfl_xor(mx, 1, 64));
    mx = fmaxf(mx, __shfl_xor(mx, 2, 64));
    float s = __expf(o0 - mx) + __expf(o1 - mx) + __expf(o2 - mx) + __expf(o3 - mx);
    s += __shfl_xor(s, 1, 64);
    s += __shfl_xor(s, 2, 64);
    float l = mx + __logf(s);
    if (e16 == 0) {
        float4 r;
        r.x = o0 - l;
        r.y = o1 - l;
        r.z = o2 - l;
        r.w = o3 - l;
        ((float4*)out)[(size_t)v * 4 + cq] = r;
    }
}

// ---------------- launch ----------------

extern "C" void kernel_launch(void* const* d_in, const int* in_sizes, int n_in,
                              void* d_out, int out_size, void* d_ws, size_t ws_size,
                              hipStream_t stream) {
    const float* x = (const float*)d_in[0];
    const int* ei = (const int*)d_in[1];
    const float* W1 = (const float*)d_in[2];
    const float* asrc1 = (const float*)d_in[3];
    const float* adst1 = (const float*)d_in[4];
    const float* b1 = (const float*)d_in[5];
    const float* W2 = (const float*)d_in[6];
    const float* asrc2 = (const float*)d_in[7];
    const float* adst2 = (const float*)d_in[8];
    const float* b2 = (const float*)d_in[9];
    float* out = (float*)d_out;

    int n = in_sizes[0] / 256;   // 50000
    int E = in_sizes[1] / 2;     // 800000
    int P = E + n;
    const int* src = ei;
    const int* dst = ei + E;
    int NB = (n + 255) / 256;

    char* p = (char*)d_ws;
    auto alloc = [&](size_t bytes) {
        void* r = (void*)p;
        p += (bytes + 255) & ~(size_t)255;
        return r;
    };
    unsigned short* h1b = (unsigned short*)alloc((size_t)n * 256 * 2);  // head-major [8][n][32]
    unsigned short* x2b = (unsigned short*)alloc((size_t)n * 256 * 2);
    unsigned short* W1t = (unsigned short*)alloc((size_t)256 * 256 * 2);
    unsigned short* W2t = (unsigned short*)alloc((size_t)16 * 256 * 2);
    float* als1 = (float*)alloc((size_t)n * 8 * 4);  // head-major [8][n]
    float* ald1 = (float*)alloc((size_t)n * 8 * 4);  // head-major [8][n]
    unsigned short* h2b = (unsigned short*)alloc((size_t)n * 16 * 2);
    float* als2 = (float*)alloc((size_t)n * 4);
    float* ald2 = (float*)alloc((size_t)n * 4);
    int* deg = (int*)alloc((size_t)n * 4);
    int* offs = (int*)alloc((size_t)(n + 1) * 4);
    int* cursor = (int*)alloc((size_t)n * 4);
    int* stmp = (int*)alloc((size_t)n * 4);
    int* blocksum = (int*)alloc((size_t)NB * 4);
    int* blockpre = (int*)alloc((size_t)NB * 4);
    int* csr = (int*)alloc((size_t)P * 4);

    // CSR build
    hipMemsetAsync(deg, 0, (size_t)n * 4, stream);
    k_hist<<<(E + 255) / 256, 256, 0, stream>>>(dst, deg, E);
    k_scanA<<<NB, 256, 0, stream>>>(deg, stmp, blocksum, n);
    k_scanB<<<1, 256, 0, stream>>>(blocksum, blockpre, NB);
    k_scanC<<<NB, 256, 0, stream>>>(stmp, blockpre, offs, cursor, n, P);
    k_scatter<<<(P + 255) / 256, 256, 0, stream>>>(src, dst, cursor, csr, E, n);

    // layer 1
    k_prepw<<<272, 256, 0, stream>>>(W1, W2, W1t, W2t);
    k_gemm1<<<dim3((n + 127) / 128, 2), 256, 0, stream>>>(x, W1t, h1b, n);
    k_al1<<<(n + 3) / 4, 256, 0, stream>>>(h1b, asrc1, adst1, als1, ald1, n);
    k_agg1<<<2048, 256, 0, stream>>>(csr, offs, als1, ald1, h1b, b1, x2b, n);

    // layer 2
    k_gemm2<<<(n + 63) / 64, 256, 0, stream>>>(x2b, W2t, asrc2, adst2, h2b, als2, ald2, n);
    k_agg2<<<(n + 3) / 4, 256, 0, stream>>>(csr, offs, als2, ald2, h2b, b2, out, n);
}

// Round 4
// 338.499 us; speedup vs baseline: 1.2007x; 1.2007x over previous
//
#include <hip/hip_runtime.h>
#include <hip/hip_bf16.h>

// GATNet v12: revert k_agg1 to v10 wave-per-node structure (v11's head-split
// proved L2-residency works - FETCH 220->45MB - but 8x per-node overhead
// amplification cost 2.3x; traffic isn't the binding constraint, latency
// structure is). k_agg1 inner loop deepened to 8 rows in flight.
// k_gemm1 retiled to 64x256 with fused attention logits (halves A fp32
// traffic, eliminates k_al1's 25.6MB h1b re-read + one launch).

#define LRELU(x) ((x) > 0.f ? (x) : 0.2f * (x))

typedef __attribute__((ext_vector_type(8))) short short8;
typedef __attribute__((ext_vector_type(8))) unsigned short ushort8;
typedef __attribute__((ext_vector_type(4))) float f32x4;

__device__ inline unsigned short f2b(float f) {
    __hip_bfloat16 h = __float2bfloat16(f);
    return *reinterpret_cast<unsigned short*>(&h);
}
__device__ inline float b2f(unsigned short u) {
    __hip_bfloat16 h;
    *reinterpret_cast<unsigned short*>(&h) = u;
    return __bfloat162float(h);
}
__device__ inline float bl(unsigned int u) { return __uint_as_float(u << 16); }
__device__ inline float bh(unsigned int u) { return __uint_as_float(u & 0xffff0000u); }

// ---------------- CSR build ----------------

__global__ void k_hist(const int* __restrict__ dst, int* deg, int E) {
    int i = blockIdx.x * blockDim.x + threadIdx.x;
    if (i < E) atomicAdd(&deg[dst[i]], 1);
}

__global__ __launch_bounds__(256) void k_scanA(const int* __restrict__ deg,
                                               int* __restrict__ tmp,
                                               int* __restrict__ blocksum, int n) {
    __shared__ int sc[256];
    int b = blockIdx.x, t = threadIdx.x;
    int i = b * 256 + t;
    int v = (i < n) ? deg[i] + 1 : 0;   // +1: self loop
    sc[t] = v;
    __syncthreads();
    for (int off = 1; off < 256; off <<= 1) {
        int x = 0;
        if (t >= off) x = sc[t - off];
        __syncthreads();
        sc[t] += x;
        __syncthreads();
    }
    if (i < n) tmp[i] = sc[t] - v;
    if (t == 255) blocksum[b] = sc[255];
}

__global__ __launch_bounds__(256) void k_scanB(const int* __restrict__ blocksum,
                                               int* __restrict__ blockpre, int nb) {
    __shared__ int sc[256];
    int t = threadIdx.x;
    int v = (t < nb) ? blocksum[t] : 0;
    sc[t] = v;
    __syncthreads();
    for (int off = 1; off < 256; off <<= 1) {
        int x = 0;
        if (t >= off) x = sc[t - off];
        __syncthreads();
        sc[t] += x;
        __syncthreads();
    }
    if (t < nb) blockpre[t] = sc[t] - v;
}

__global__ __launch_bounds__(256) void k_scanC(const int* __restrict__ tmp,
                                               const int* __restrict__ blockpre,
                                               int* __restrict__ offs,
                                               int* __restrict__ cursor, int n, int P) {
    int b = blockIdx.x, t = threadIdx.x;
    int i = b * 256 + t;
    if (i < n) {
        int o = tmp[i] + blockpre[b];
        offs[i] = o;
        cursor[i] = o;
    }
    if (i == 0) offs[n] = P;
}

__global__ void k_scatter(const int* __restrict__ src, const int* __restrict__ dst,
                          int* cursor, int* __restrict__ csr, int E, int n) {
    int i = blockIdx.x * blockDim.x + threadIdx.x;
    int s, d;
    if (i < E) {
        s = src[i];
        d = dst[i];
    } else if (i < E + n) {
        s = i - E;
        d = s;
    } else {
        return;
    }
    int p = atomicAdd(&cursor[d], 1);
    csr[p] = s;
}

// ---------------- weight prep: W1t[256][256], W2t[16][256] bf16 (merged) ----

__global__ __launch_bounds__(256) void k_prepw(const float* __restrict__ W1,
                                               const float* __restrict__ W2,
                                               unsigned short* __restrict__ W1t,
                                               unsigned short* __restrict__ W2t) {
    int b = blockIdx.x;
    if (b < 256) {
        int k = b, nn = threadIdx.x;
        W1t[nn * 256 + k] = f2b(W1[k * 256 + nn]);
    } else {
        int nn = b - 256, k = threadIdx.x;
        W2t[nn * 256 + k] = f2b(W2[k * 16 + nn]);
    }
}

// ---------------- GEMM1 (MFMA bf16) + fused layer-1 attention logits --------
// 64x256 tile, 256 thr = 4 waves; wave w: rows 16w..16w+15, all 256 cols
// (16 col-tiles). A fp32 read exactly once. Epilogue computes als/ald from
// fp32 accumulators (replaces k_al1) via width-16 shfl reductions.

__global__ __launch_bounds__(256) void k_gemm1(const float* __restrict__ A,
                                               const unsigned short* __restrict__ Wt,
                                               const float* __restrict__ asrc,
                                               const float* __restrict__ adst,
                                               unsigned short* __restrict__ h1b,
                                               float* __restrict__ als,
                                               float* __restrict__ ald, int M) {
    __shared__ unsigned short As[64][36];
    __shared__ unsigned short Bs[256][36];
    int t = threadIdx.x;
    int r0 = blockIdx.x * 64;
    int lane = t & 63, w = t >> 6;
    int lane15 = lane & 15, quad = lane >> 4;

    f32x4 acc[16];
#pragma unroll
    for (int j = 0; j < 16; j++) acc[j] = (f32x4)0.f;

    for (int k0 = 0; k0 < 256; k0 += 32) {
        {
            int srow = t >> 2, spart = t & 3;
            int row = r0 + srow;
            ushort8 pk;
            if (row < M) {
                const float4* sp = (const float4*)&A[(size_t)row * 256 + k0 + spart * 8];
                float4 f0 = sp[0], f1 = sp[1];
                pk[0] = f2b(f0.x); pk[1] = f2b(f0.y); pk[2] = f2b(f0.z); pk[3] = f2b(f0.w);
                pk[4] = f2b(f1.x); pk[5] = f2b(f1.y); pk[6] = f2b(f1.z); pk[7] = f2b(f1.w);
            } else {
                pk = (ushort8)0;
            }
            *(ushort8*)&As[srow][spart * 8] = pk;
            const ushort8* bp = (const ushort8*)&Wt[(size_t)t * 256 + k0];
            ushort8 b0 = bp[0], b1 = bp[1], b2 = bp[2], b3 = bp[3];
            *(ushort8*)&Bs[t][0] = b0;
            *(ushort8*)&Bs[t][8] = b1;
            *(ushort8*)&Bs[t][16] = b2;
            *(ushort8*)&Bs[t][24] = b3;
        }
        __syncthreads();
        short8 af = *(const short8*)&As[w * 16 + lane15][quad * 8];
#pragma unroll
        for (int j = 0; j < 16; j++) {
            short8 bf = *(const short8*)&Bs[j * 16 + lane15][quad * 8];
            acc[j] = __builtin_amdgcn_mfma_f32_16x16x32_bf16(af, bf, acc[j], 0, 0, 0);
        }
        __syncthreads();
    }
    // asrc/adst flat [8][32] == indexed by col directly
    float asv[16], adv[16];
#pragma unroll
    for (int j = 0; j < 16; j++) {
        asv[j] = asrc[j * 16 + lane15];
        adv[j] = adst[j * 16 + lane15];
    }
    int row0w = r0 + w * 16 + quad * 4;
#pragma unroll
    for (int r = 0; r < 4; r++) {
        int row = row0w + r;
        bool ok = row < M;
        if (ok) {
#pragma unroll
            for (int j = 0; j < 16; j++)
                h1b[(size_t)row * 256 + j * 16 + lane15] = f2b(acc[j][r]);
        }
#pragma unroll
        for (int h = 0; h < 8; h++) {
            float ps = acc[2 * h][r] * asv[2 * h] + acc[2 * h + 1][r] * asv[2 * h + 1];
            float pd = acc[2 * h][r] * adv[2 * h] + acc[2 * h + 1][r] * adv[2 * h + 1];
#pragma unroll
            for (int off = 1; off < 16; off <<= 1) {
                ps += __shfl_xor(ps, off, 16);
                pd += __shfl_xor(pd, off, 16);
            }
            if (ok && lane15 == 0) {
                als[(size_t)row * 8 + h] = ps;
                ald[(size_t)row * 8 + h] = pd;
            }
        }
    }
}

// ---------------- layer-1 aggregate: wave per node, 8 rows in flight --------
// 256 thr = 4 independent waves, one node each. Lane owns cols [4L,4L+4).
// Phase A (all 64 lanes): edge e2=lane>>1, half=lane&1 -> 4 head-weights into
// LDS ws[e][8], su[e]. Wave-synchronous handoff (lgkmcnt fence, no barrier).
// Phase B: 8 rows/iter, each row = one fully-coalesced 512B wave load.
// Epilogue: pure per-lane (no shfl/LDS), uint2 store.

__global__ __launch_bounds__(256) void k_agg1(const int* __restrict__ csr,
                                              const int* __restrict__ offs,
                                              const float* __restrict__ als,
                                              const float* __restrict__ aldg,
                                              const unsigned short* __restrict__ h1b,
                                              const float* __restrict__ b1,
                                              unsigned short* __restrict__ x2b, int n) {
    int wid = threadIdx.x >> 6;
    int v = blockIdx.x * 4 + wid;
    if (v >= n) return;
    int lane = threadIdx.x & 63;
    int start = offs[v];
    int deg = offs[v + 1] - start;
    __shared__ int su_s[4][32];
    __shared__ float ws_s[4][32 * 8];
    int* su = su_s[wid];
    float* ws = ws_s[wid];
    int h = lane >> 3;                    // head for phase B (cols 4*lane..)
    int e2 = lane >> 1, half = lane & 1;  // phase A mapping
    float4 aldv4 = ((const float4*)(aldg + (size_t)v * 8))[half];
    float a0 = 0.f, a1 = 0.f, a2 = 0.f, a3 = 0.f, wsum = 0.f;
    for (int base = 0; base < deg; base += 32) {
        int cnt = min(32, deg - base);
        int cnt8 = (cnt + 7) & ~7;
        __builtin_amdgcn_wave_barrier();
        {
            int u = v;
            float4 w4 = make_float4(0.f, 0.f, 0.f, 0.f);
            if (e2 < cnt) {
                u = csr[start + base + e2];
                float4 x0 = ((const float4*)(als + (size_t)u * 8))[half];
                w4.x = __expf(LRELU(x0.x + aldv4.x));
                w4.y = __expf(LRELU(x0.y + aldv4.y));
                w4.z = __expf(LRELU(x0.z + aldv4.z));
                w4.w = __expf(LRELU(x0.w + aldv4.w));
            }
            if (half == 0) su[e2] = u;
            *(float4*)&ws[e2 * 8 + half * 4] = w4;
        }
        __builtin_amdgcn_wave_barrier();
        asm volatile("s_waitcnt lgkmcnt(0)" ::: "memory");
        __builtin_amdgcn_wave_barrier();
        for (int e = 0; e < cnt8; e += 8) {
            int u0 = su[e + 0], u1 = su[e + 1], u2 = su[e + 2], u3 = su[e + 3];
            int u4 = su[e + 4], u5 = su[e + 5], u6 = su[e + 6], u7 = su[e + 7];
            float w0 = ws[(e + 0) * 8 + h];
            float w1 = ws[(e + 1) * 8 + h];
            float w2 = ws[(e + 2) * 8 + h];
            float w3 = ws[(e + 3) * 8 + h];
            float w4 = ws[(e + 4) * 8 + h];
            float w5 = ws[(e + 5) * 8 + h];
            float w6 = ws[(e + 6) * 8 + h];
            float w7 = ws[(e + 7) * 8 + h];
            uint2 p0 = ((const uint2*)(h1b + (size_t)u0 * 256))[lane];
            uint2 p1 = ((const uint2*)(h1b + (size_t)u1 * 256))[lane];
            uint2 p2 = ((const uint2*)(h1b + (size_t)u2 * 256))[lane];
            uint2 p3 = ((const uint2*)(h1b + (size_t)u3 * 256))[lane];
            uint2 p4 = ((const uint2*)(h1b + (size_t)u4 * 256))[lane];
            uint2 p5 = ((const uint2*)(h1b + (size_t)u5 * 256))[lane];
            uint2 p6 = ((const uint2*)(h1b + (size_t)u6 * 256))[lane];
            uint2 p7 = ((const uint2*)(h1b + (size_t)u7 * 256))[lane];
            a0 += w0 * bl(p0.x); a1 += w0 * bh(p0.x);
            a2 += w0 * bl(p0.y); a3 += w0 * bh(p0.y);
            a0 += w1 * bl(p1.x); a1 += w1 * bh(p1.x);
            a2 += w1 * bl(p1.y); a3 += w1 * bh(p1.y);
            a0 += w2 * bl(p2.x); a1 += w2 * bh(p2.x);
            a2 += w2 * bl(p2.y); a3 += w2 * bh(p2.y);
            a0 += w3 * bl(p3.x); a1 += w3 * bh(p3.x);
            a2 += w3 * bl(p3.y); a3 += w3 * bh(p3.y);
            a0 += w4 * bl(p4.x); a1 += w4 * bh(p4.x);
            a2 += w4 * bl(p4.y); a3 += w4 * bh(p4.y);
            a0 += w5 * bl(p5.x); a1 += w5 * bh(p5.x);
            a2 += w5 * bl(p5.y); a3 += w5 * bh(p5.y);
            a0 += w6 * bl(p6.x); a1 += w6 * bh(p6.x);
            a2 += w6 * bl(p6.y); a3 += w6 * bh(p6.y);
            a0 += w7 * bl(p7.x); a1 += w7 * bh(p7.x);
            a2 += w7 * bl(p7.y); a3 += w7 * bh(p7.y);
            wsum += ((w0 + w1) + (w2 + w3)) + ((w4 + w5) + (w6 + w7));
        }
        __builtin_amdgcn_wave_barrier();
    }
    float inv = 1.0f / wsum;
    float4 bb = ((const float4*)b1)[lane];
    float o0 = fmaxf(a0 * inv + bb.x, 0.f);
    float o1 = fmaxf(a1 * inv + bb.y, 0.f);
    float o2 = fmaxf(a2 * inv + bb.z, 0.f);
    float o3 = fmaxf(a3 * inv + bb.w, 0.f);
    uint2 o;
    o.x = (unsigned int)f2b(o0) | ((unsigned int)f2b(o1) << 16);
    o.y = (unsigned int)f2b(o2) | ((unsigned int)f2b(o3) << 16);
    ((uint2*)(x2b + (size_t)v * 256))[lane] = o;
}

// ---------------- GEMM2 (MFMA) + fused layer-2 logits ----------------------

__global__ __launch_bounds__(256) void k_gemm2(const unsigned short* __restrict__ Xb,
                                               const unsigned short* __restrict__ W2t,
                                               const float* __restrict__ asrc,
                                               const float* __restrict__ adst,
                                               unsigned short* __restrict__ h2b,
                                               float* __restrict__ als,
                                               float* __restrict__ ald, int n) {
    int t = threadIdx.x;
    int lane = t & 63, w = t >> 6;
    int lane15 = lane & 15, quad = lane >> 4;
    int row0 = blockIdx.x * 64 + w * 16;
    f32x4 acc = (f32x4)0.f;
#pragma unroll
    for (int k0 = 0; k0 < 256; k0 += 32) {
        short8 a = *(const short8*)&Xb[(size_t)(row0 + lane15) * 256 + k0 + quad * 8];
        short8 b = *(const short8*)&W2t[lane15 * 256 + k0 + quad * 8];
        acc = __builtin_amdgcn_mfma_f32_16x16x32_bf16(a, b, acc, 0, 0, 0);
    }
    float asv = asrc[lane15], adv = adst[lane15];
#pragma unroll
    for (int r = 0; r < 4; r++) {
        int row = row0 + quad * 4 + r;
        float hv = acc[r];
        float ps = hv * asv, pd = hv * adv;
#pragma unroll
        for (int off = 1; off < 16; off <<= 1) {
            ps += __shfl_xor(ps, off, 16);
            pd += __shfl_xor(pd, off, 16);
        }
        if (row < n) {
            h2b[(size_t)row * 16 + lane15] = f2b(hv);
            if (lane15 == 0) {
                als[row] = ps;
                ald[row] = pd;
            }
        }
    }
}

// ---------------- layer-2 aggregate: wave per node + log_softmax ------------

__global__ __launch_bounds__(256) void k_agg2(const int* __restrict__ csr,
                                              const int* __restrict__ offs,
                                              const float* __restrict__ als,
                                              const float* __restrict__ aldg,
                                              const unsigned short* __restrict__ h2b,
                                              const float* __restrict__ b2,
                                              float* __restrict__ out, int n) {
    int wid = threadIdx.x >> 6;
    int v = blockIdx.x * 4 + wid;
    if (v >= n) return;
    int lane = threadIdx.x & 63;
    int start = offs[v];
    int deg = offs[v + 1] - start;
    __shared__ int su_s[4][32];
    __shared__ float ws_s[4][32];
    int* su = su_s[wid];
    float* ws = ws_s[wid];
    float aldv = aldg[v];
    int e16 = lane >> 2, cq = lane & 3;
    float a0 = 0.f, a1 = 0.f, a2 = 0.f, a3 = 0.f, wsum = 0.f;
    for (int base = 0; base < deg; base += 32) {
        int cnt = min(32, deg - base);
        int cnt16 = (cnt + 15) & ~15;
        __builtin_amdgcn_wave_barrier();
        if (lane < 32) {
            int u = v;
            float wv = 0.f;
            if (lane < cnt) {
                u = csr[start + base + lane];
                float x = als[u] + aldv;
                wv = __expf(LRELU(x));
            }
            su[lane] = u;
            ws[lane] = wv;
        }
        __builtin_amdgcn_wave_barrier();
        asm volatile("s_waitcnt lgkmcnt(0)" ::: "memory");
        __builtin_amdgcn_wave_barrier();
        for (int e = 0; e < cnt16; e += 16) {
            int u = su[e + e16];
            float wv = ws[e + e16];
            uint2 pk = ((const uint2*)(h2b + (size_t)u * 16))[cq];
            a0 += wv * bl(pk.x); a1 += wv * bh(pk.x);
            a2 += wv * bl(pk.y); a3 += wv * bh(pk.y);
            wsum += wv;
        }
        __builtin_amdgcn_wave_barrier();
    }
    // reduce over 16 edge slots (lane bits 2..5)
#pragma unroll
    for (int off = 4; off < 64; off <<= 1) {
        a0 += __shfl_xor(a0, off, 64);
        a1 += __shfl_xor(a1, off, 64);
        a2 += __shfl_xor(a2, off, 64);
        a3 += __shfl_xor(a3, off, 64);
        wsum += __shfl_xor(wsum, off, 64);
    }
    float inv = 1.0f / wsum;
    float4 bb = ((const float4*)b2)[cq];
    float o0 = a0 * inv + bb.x;
    float o1 = a1 * inv + bb.y;
    float o2 = a2 * inv + bb.z;
    float o3 = a3 * inv + bb.w;
    // log_softmax over 16 cols held as 4 lanes (cq) x 4 cols
    float mx = fmaxf(fmaxf(o0, o1), fmaxf(o2, o3));
    mx = fmaxf(mx, __shfl_xor(mx, 1, 64));
    mx = fmaxf(mx, __shfl_xor(mx, 2, 64));
    float s = __expf(o0 - mx) + __expf(o1 - mx) + __expf(o2 - mx) + __expf(o3 - mx);
    s += __shfl_xor(s, 1, 64);
    s += __shfl_xor(s, 2, 64);
    float l = mx + __logf(s);
    if (e16 == 0) {
        float4 r;
        r.x = o0 - l;
        r.y = o1 - l;
        r.z = o2 - l;
        r.w = o3 - l;
        ((float4*)out)[(size_t)v * 4 + cq] = r;
    }
}

// ---------------- launch ----------------

extern "C" void kernel_launch(void* const* d_in, const int* in_sizes, int n_in,
                              void* d_out, int out_size, void* d_ws, size_t ws_size,
                              hipStream_t stream) {
    const float* x = (const float*)d_in[0];
    const int* ei = (const int*)d_in[1];
    const float* W1 = (const float*)d_in[2];
    const float* asrc1 = (const float*)d_in[3];
    const float* adst1 = (const float*)d_in[4];
    const float* b1 = (const float*)d_in[5];
    const float* W2 = (const float*)d_in[6];
    const float* asrc2 = (const float*)d_in[7];
    const float* adst2 = (const float*)d_in[8];
    const float* b2 = (const float*)d_in[9];
    float* out = (float*)d_out;

    int n = in_sizes[0] / 256;   // 50000
    int E = in_sizes[1] / 2;     // 800000
    int P = E + n;
    const int* src = ei;
    const int* dst = ei + E;
    int NB = (n + 255) / 256;

    char* p = (char*)d_ws;
    auto alloc = [&](size_t bytes) {
        void* r = (void*)p;
        p += (bytes + 255) & ~(size_t)255;
        return r;
    };
    unsigned short* h1b = (unsigned short*)alloc((size_t)n * 256 * 2);
    unsigned short* x2b = (unsigned short*)alloc((size_t)n * 256 * 2);
    unsigned short* W1t = (unsigned short*)alloc((size_t)256 * 256 * 2);
    unsigned short* W2t = (unsigned short*)alloc((size_t)16 * 256 * 2);
    float* als1 = (float*)alloc((size_t)n * 8 * 4);
    float* ald1 = (float*)alloc((size_t)n * 8 * 4);
    unsigned short* h2b = (unsigned short*)alloc((size_t)n * 16 * 2);
    float* als2 = (float*)alloc((size_t)n * 4);
    float* ald2 = (float*)alloc((size_t)n * 4);
    int* deg = (int*)alloc((size_t)n * 4);
    int* offs = (int*)alloc((size_t)(n + 1) * 4);
    int* cursor = (int*)alloc((size_t)n * 4);
    int* stmp = (int*)alloc((size_t)n * 4);
    int* blocksum = (int*)alloc((size_t)NB * 4);
    int* blockpre = (int*)alloc((size_t)NB * 4);
    int* csr = (int*)alloc((size_t)P * 4);

    // CSR build
    hipMemsetAsync(deg, 0, (size_t)n * 4, stream);
    k_hist<<<(E + 255) / 256, 256, 0, stream>>>(dst, deg, E);
    k_scanA<<<NB, 256, 0, stream>>>(deg, stmp, blocksum, n);
    k_scanB<<<1, 256, 0, stream>>>(blocksum, blockpre, NB);
    k_scanC<<<NB, 256, 0, stream>>>(stmp, blockpre, offs, cursor, n, P);
    k_scatter<<<(P + 255) / 256, 256, 0, stream>>>(src, dst, cursor, csr, E, n);

    // layer 1 (gemm1 fuses attention logits; k_al1 eliminated)
    k_prepw<<<272, 256, 0, stream>>>(W1, W2, W1t, W2t);
    k_gemm1<<<(n + 63) / 64, 256, 0, stream>>>(x, W1t, asrc1, adst1, h1b, als1, ald1, n);
    k_agg1<<<(n + 3) / 4, 256, 0, stream>>>(csr, offs, als1, ald1, h1b, b1, x2b, n);

    // layer 2
    k_gemm2<<<(n + 63) / 64, 256, 0, stream>>>(x2b, W2t, asrc2, adst2, h2b, als2, ald2, n);
    k_agg2<<<(n + 3) / 4, 256, 0, stream>>>(csr, offs, als2, ald2, h2b, b2, out, n);
}

// Round 6
// 327.386 us; speedup vs baseline: 1.2415x; 1.0339x over previous
//
#include <hip/hip_runtime.h>
#include <hip/hip_bf16.h>

// GATNet v13 (resubmit; round-5 bench was an infra failure, not a kernel
// fault). "Self-service weights" aggregation. v9-v12 showed k_agg1 is
// invariant (~67.5us) to inner-loop width; remaining in-kernel serialization
// is phase A (csr->als->exp->LDS->fence per chunk). v13 deletes phase A:
// each lane computes its own head's weight inline (csr via scalar load,
// als[u*8+h] 32B coalesced gather, exp x8-redundant) -> no LDS, no fences,
// 4 independent load chains, ~40 VGPR. Same for k_agg2. k_gemm1/k_al1
// reverted to v10 structure (v12's 64x256 fused tile was +10.6us net).

#define LRELU(x) ((x) > 0.f ? (x) : 0.2f * (x))

typedef __attribute__((ext_vector_type(8))) short short8;
typedef __attribute__((ext_vector_type(8))) unsigned short ushort8;
typedef __attribute__((ext_vector_type(4))) float f32x4;

__device__ inline unsigned short f2b(float f) {
    __hip_bfloat16 h = __float2bfloat16(f);
    return *reinterpret_cast<unsigned short*>(&h);
}
__device__ inline float b2f(unsigned short u) {
    __hip_bfloat16 h;
    *reinterpret_cast<unsigned short*>(&h) = u;
    return __bfloat162float(h);
}
__device__ inline float bl(unsigned int u) { return __uint_as_float(u << 16); }
__device__ inline float bh(unsigned int u) { return __uint_as_float(u & 0xffff0000u); }

// ---------------- CSR build ----------------

__global__ void k_hist(const int* __restrict__ dst, int* deg, int E) {
    int i = blockIdx.x * blockDim.x + threadIdx.x;
    if (i < E) atomicAdd(&deg[dst[i]], 1);
}

__global__ __launch_bounds__(256) void k_scanA(const int* __restrict__ deg,
                                               int* __restrict__ tmp,
                                               int* __restrict__ blocksum, int n) {
    __shared__ int sc[256];
    int b = blockIdx.x, t = threadIdx.x;
    int i = b * 256 + t;
    int v = (i < n) ? deg[i] + 1 : 0;   // +1: self loop
    sc[t] = v;
    __syncthreads();
    for (int off = 1; off < 256; off <<= 1) {
        int x = 0;
        if (t >= off) x = sc[t - off];
        __syncthreads();
        sc[t] += x;
        __syncthreads();
    }
    if (i < n) tmp[i] = sc[t] - v;
    if (t == 255) blocksum[b] = sc[255];
}

__global__ __launch_bounds__(256) void k_scanB(const int* __restrict__ blocksum,
                                               int* __restrict__ blockpre, int nb) {
    __shared__ int sc[256];
    int t = threadIdx.x;
    int v = (t < nb) ? blocksum[t] : 0;
    sc[t] = v;
    __syncthreads();
    for (int off = 1; off < 256; off <<= 1) {
        int x = 0;
        if (t >= off) x = sc[t - off];
        __syncthreads();
        sc[t] += x;
        __syncthreads();
    }
    if (t < nb) blockpre[t] = sc[t] - v;
}

__global__ __launch_bounds__(256) void k_scanC(const int* __restrict__ tmp,
                                               const int* __restrict__ blockpre,
                                               int* __restrict__ offs,
                                               int* __restrict__ cursor, int n, int P) {
    int b = blockIdx.x, t = threadIdx.x;
    int i = b * 256 + t;
    if (i < n) {
        int o = tmp[i] + blockpre[b];
        offs[i] = o;
        cursor[i] = o;
    }
    if (i == 0) offs[n] = P;
}

__global__ void k_scatter(const int* __restrict__ src, const int* __restrict__ dst,
                          int* cursor, int* __restrict__ csr, int E, int n) {
    int i = blockIdx.x * blockDim.x + threadIdx.x;
    int s, d;
    if (i < E) {
        s = src[i];
        d = dst[i];
    } else if (i < E + n) {
        s = i - E;
        d = s;
    } else {
        return;
    }
    int p = atomicAdd(&cursor[d], 1);
    csr[p] = s;
}

// ---------------- weight prep: W1t[256][256], W2t[16][256] bf16 (merged) ----

__global__ __launch_bounds__(256) void k_prepw(const float* __restrict__ W1,
                                               const float* __restrict__ W2,
                                               unsigned short* __restrict__ W1t,
                                               unsigned short* __restrict__ W2t) {
    int b = blockIdx.x;
    if (b < 256) {
        int k = b, nn = threadIdx.x;
        W1t[nn * 256 + k] = f2b(W1[k * 256 + nn]);
    } else {
        int nn = b - 256, k = threadIdx.x;
        W2t[nn * 256 + k] = f2b(W2[k * 16 + nn]);
    }
}

// ---------------- GEMM1 (MFMA bf16): h1b[M,256] = bf16(A[M,256] @ W1) -------

__global__ __launch_bounds__(256) void k_gemm1(const float* __restrict__ A,
                                               const unsigned short* __restrict__ Wt,
                                               unsigned short* __restrict__ h1b, int M) {
    __shared__ unsigned short As[128][40];
    __shared__ unsigned short Bs[128][40];
    int t = threadIdx.x;
    int r0 = blockIdx.x * 128, c0 = blockIdx.y * 128;
    int srow = t >> 1, shalf = t & 1;
    int lane = t & 63, w = t >> 6;
    int lane15 = lane & 15, quad = lane >> 4;
    int rbw = (w & 1) * 64, cbw = (w >> 1) * 64;

    f32x4 acc[4][4];
#pragma unroll
    for (int i = 0; i < 4; i++)
#pragma unroll
        for (int j = 0; j < 4; j++) acc[i][j] = (f32x4)0.f;

    for (int k0 = 0; k0 < 256; k0 += 32) {
        {
            int row = r0 + srow;
            ushort8 p0, p1;
            if (row < M) {
                const float4* sp = (const float4*)&A[(size_t)row * 256 + k0 + shalf * 16];
                float4 f0 = sp[0], f1 = sp[1], f2 = sp[2], f3 = sp[3];
                p0[0] = f2b(f0.x); p0[1] = f2b(f0.y); p0[2] = f2b(f0.z); p0[3] = f2b(f0.w);
                p0[4] = f2b(f1.x); p0[5] = f2b(f1.y); p0[6] = f2b(f1.z); p0[7] = f2b(f1.w);
                p1[0] = f2b(f2.x); p1[1] = f2b(f2.y); p1[2] = f2b(f2.z); p1[3] = f2b(f2.w);
                p1[4] = f2b(f3.x); p1[5] = f2b(f3.y); p1[6] = f2b(f3.z); p1[7] = f2b(f3.w);
            } else {
                p0 = (ushort8)0; p1 = (ushort8)0;
            }
            *(ushort8*)&As[srow][shalf * 16] = p0;
            *(ushort8*)&As[srow][shalf * 16 + 8] = p1;
            const ushort8* bp = (const ushort8*)&Wt[(size_t)(c0 + srow) * 256 + k0 + shalf * 16];
            *(ushort8*)&Bs[srow][shalf * 16] = bp[0];
            *(ushort8*)&Bs[srow][shalf * 16 + 8] = bp[1];
        }
        __syncthreads();
        short8 af[4], bf[4];
#pragma unroll
        for (int i = 0; i < 4; i++)
            af[i] = *(const short8*)&As[rbw + i * 16 + lane15][quad * 8];
#pragma unroll
        for (int j = 0; j < 4; j++)
            bf[j] = *(const short8*)&Bs[cbw + j * 16 + lane15][quad * 8];
#pragma unroll
        for (int i = 0; i < 4; i++)
#pragma unroll
            for (int j = 0; j < 4; j++)
                acc[i][j] = __builtin_amdgcn_mfma_f32_16x16x32_bf16(af[i], bf[j], acc[i][j], 0, 0, 0);
        __syncthreads();
    }
#pragma unroll
    for (int i = 0; i < 4; i++) {
        int rowb = r0 + rbw + i * 16 + quad * 4;
#pragma unroll
        for (int j = 0; j < 4; j++) {
            int col = c0 + cbw + j * 16 + lane15;
#pragma unroll
            for (int r = 0; r < 4; r++) {
                int row = rowb + r;
                if (row < M) h1b[(size_t)row * 256 + col] = f2b(acc[i][j][r]);
            }
        }
    }
}

// ---------------- attention logits layer 1: wave per node, 4 nodes/block ----

__global__ __launch_bounds__(256) void k_al1(const unsigned short* __restrict__ h1b,
                                             const float* __restrict__ asrc,
                                             const float* __restrict__ adst,
                                             float* __restrict__ als,
                                             float* __restrict__ ald, int n) {
    int v = blockIdx.x * 4 + (threadIdx.x >> 6);
    if (v >= n) return;
    int lane = threadIdx.x & 63;
    const uint2* hp = (const uint2*)(h1b + (size_t)v * 256);
    uint2 pk = hp[lane];
    float f0 = bl(pk.x);
    float f1 = bh(pk.x);
    float f2 = bl(pk.y);
    float f3 = bh(pk.y);
    float4 a_s = ((const float4*)asrc)[lane];
    float4 a_d = ((const float4*)adst)[lane];
    float ps = f0 * a_s.x + f1 * a_s.y + f2 * a_s.z + f3 * a_s.w;
    float pd = f0 * a_d.x + f1 * a_d.y + f2 * a_d.z + f3 * a_d.w;
#pragma unroll
    for (int off = 1; off < 8; off <<= 1) {
        ps += __shfl_xor(ps, off, 64);
        pd += __shfl_xor(pd, off, 64);
    }
    if ((lane & 7) == 0) {
        int h = lane >> 3;
        als[v * 8 + h] = ps;
        ald[v * 8 + h] = pd;
    }
}

// ---------------- layer-1 aggregate: self-service weights, no LDS/fences ----
// 256 thr = 4 independent waves, one node each. Lane owns cols [4L,4L+4),
// head h = L>>3. Per edge: u via scalar load (wave-uniform csr base),
// w = exp(lrelu(als[u*8+h] + ald_h)) computed per-lane (x8 redundant, 32B
// coalesced als gather), row = 512B coalesced uint2 load. 4 independent
// chains in flight; tail via index-clamp + w=0 (inert).

__global__ __launch_bounds__(256) void k_agg1(const int* __restrict__ csr,
                                              const int* __restrict__ offs,
                                              const float* __restrict__ als,
                                              const float* __restrict__ aldg,
                                              const unsigned short* __restrict__ h1b,
                                              const float* __restrict__ b1,
                                              unsigned short* __restrict__ x2b, int n) {
    int wid = threadIdx.x >> 6;
    int v = blockIdx.x * 4 + wid;
    if (v >= n) return;
    int lane = threadIdx.x & 63;
    int h = lane >> 3;
    int start = __builtin_amdgcn_readfirstlane(offs[v]);
    int deg = __builtin_amdgcn_readfirstlane(offs[v + 1]) - start;
    const int* __restrict__ cp = csr + start;
    int dm1 = deg - 1;
    float aldvh = aldg[(size_t)v * 8 + h];
    float a0 = 0.f, a1 = 0.f, a2 = 0.f, a3 = 0.f, wsum = 0.f;
    for (int e = 0; e < deg; e += 4) {
        int u0 = cp[e];                  // e < deg always
        int u1 = cp[min(e + 1, dm1)];
        int u2 = cp[min(e + 2, dm1)];
        int u3 = cp[min(e + 3, dm1)];
        uint2 p0 = ((const uint2*)(h1b + (size_t)u0 * 256))[lane];
        uint2 p1 = ((const uint2*)(h1b + (size_t)u1 * 256))[lane];
        uint2 p2 = ((const uint2*)(h1b + (size_t)u2 * 256))[lane];
        uint2 p3 = ((const uint2*)(h1b + (size_t)u3 * 256))[lane];
        float x0 = als[u0 * 8 + h];
        float x1 = als[u1 * 8 + h];
        float x2 = als[u2 * 8 + h];
        float x3 = als[u3 * 8 + h];
        float w0 = __expf(LRELU(x0 + aldvh));
        float w1 = __expf(LRELU(x1 + aldvh));
        float w2 = __expf(LRELU(x2 + aldvh));
        float w3 = __expf(LRELU(x3 + aldvh));
        if (e + 1 > dm1) w1 = 0.f;
        if (e + 2 > dm1) w2 = 0.f;
        if (e + 3 > dm1) w3 = 0.f;
        a0 += w0 * bl(p0.x); a1 += w0 * bh(p0.x);
        a2 += w0 * bl(p0.y); a3 += w0 * bh(p0.y);
        a0 += w1 * bl(p1.x); a1 += w1 * bh(p1.x);
        a2 += w1 * bl(p1.y); a3 += w1 * bh(p1.y);
        a0 += w2 * bl(p2.x); a1 += w2 * bh(p2.x);
        a2 += w2 * bl(p2.y); a3 += w2 * bh(p2.y);
        a0 += w3 * bl(p3.x); a1 += w3 * bh(p3.x);
        a2 += w3 * bl(p3.y); a3 += w3 * bh(p3.y);
        wsum += (w0 + w1) + (w2 + w3);
    }
    float inv = 1.0f / wsum;
    float4 bb = ((const float4*)b1)[lane];
    float o0 = fmaxf(a0 * inv + bb.x, 0.f);
    float o1 = fmaxf(a1 * inv + bb.y, 0.f);
    float o2 = fmaxf(a2 * inv + bb.z, 0.f);
    float o3 = fmaxf(a3 * inv + bb.w, 0.f);
    uint2 o;
    o.x = (unsigned int)f2b(o0) | ((unsigned int)f2b(o1) << 16);
    o.y = (unsigned int)f2b(o2) | ((unsigned int)f2b(o3) << 16);
    ((uint2*)(x2b + (size_t)v * 256))[lane] = o;
}

// ---------------- GEMM2 (MFMA) + fused layer-2 logits ----------------------

__global__ __launch_bounds__(256) void k_gemm2(const unsigned short* __restrict__ Xb,
                                               const unsigned short* __restrict__ W2t,
                                               const float* __restrict__ asrc,
                                               const float* __restrict__ adst,
                                               unsigned short* __restrict__ h2b,
                                               float* __restrict__ als,
                                               float* __restrict__ ald, int n) {
    int t = threadIdx.x;
    int lane = t & 63, w = t >> 6;
    int lane15 = lane & 15, quad = lane >> 4;
    int row0 = blockIdx.x * 64 + w * 16;
    f32x4 acc = (f32x4)0.f;
#pragma unroll
    for (int k0 = 0; k0 < 256; k0 += 32) {
        short8 a = *(const short8*)&Xb[(size_t)(row0 + lane15) * 256 + k0 + quad * 8];
        short8 b = *(const short8*)&W2t[lane15 * 256 + k0 + quad * 8];
        acc = __builtin_amdgcn_mfma_f32_16x16x32_bf16(a, b, acc, 0, 0, 0);
    }
    float asv = asrc[lane15], adv = adst[lane15];
#pragma unroll
    for (int r = 0; r < 4; r++) {
        int row = row0 + quad * 4 + r;
        float hv = acc[r];
        float ps = hv * asv, pd = hv * adv;
#pragma unroll
        for (int off = 1; off < 16; off <<= 1) {
            ps += __shfl_xor(ps, off, 16);
            pd += __shfl_xor(pd, off, 16);
        }
        if (row < n) {
            h2b[(size_t)row * 16 + lane15] = f2b(hv);
            if (lane15 == 0) {
                als[row] = ps;
                ald[row] = pd;
            }
        }
    }
}

// ---------------- layer-2 aggregate: self-service weights + log_softmax -----
// 64 lanes = 16 edge slots x 4 col-quads. Each lane loads its slot's u,
// computes w inline (x4 redundant), loads 8B of h2b row. Two chains/iter.
// No LDS, no fences. Slot-reduce via 4 shfls; softmax across 4 lanes.

__global__ __launch_bounds__(256) void k_agg2(const int* __restrict__ csr,
                                              const int* __restrict__ offs,
                                              const float* __restrict__ als,
                                              const float* __restrict__ aldg,
                                              const unsigned short* __restrict__ h2b,
                                              const float* __restrict__ b2,
                                              float* __restrict__ out, int n) {
    int wid = threadIdx.x >> 6;
    int v = blockIdx.x * 4 + wid;
    if (v >= n) return;
    int lane = threadIdx.x & 63;
    int slot = lane >> 2, cq = lane & 3;
    int start = __builtin_amdgcn_readfirstlane(offs[v]);
    int deg = __builtin_amdgcn_readfirstlane(offs[v + 1]) - start;
    int dm1 = deg - 1;
    float aldv = aldg[v];
    float a0 = 0.f, a1 = 0.f, a2 = 0.f, a3 = 0.f, wsum = 0.f;
    for (int e = 0; e < deg; e += 32) {
        int iA = min(e + slot, dm1);
        int iB = min(e + 16 + slot, dm1);
        int uA = csr[start + iA];
        int uB = csr[start + iB];
        uint2 pA = ((const uint2*)(h2b + (size_t)uA * 16))[cq];
        uint2 pB = ((const uint2*)(h2b + (size_t)uB * 16))[cq];
        float xA = als[uA] + aldv;
        float xB = als[uB] + aldv;
        float wA = __expf(LRELU(xA));
        float wB = __expf(LRELU(xB));
        if (e + slot > dm1) wA = 0.f;
        if (e + 16 + slot > dm1) wB = 0.f;
        a0 += wA * bl(pA.x) + wB * bl(pB.x);
        a1 += wA * bh(pA.x) + wB * bh(pB.x);
        a2 += wA * bl(pA.y) + wB * bl(pB.y);
        a3 += wA * bh(pA.y) + wB * bh(pB.y);
        wsum += wA + wB;
    }
    // reduce over 16 edge slots (lane bits 2..5)
#pragma unroll
    for (int off = 4; off < 64; off <<= 1) {
        a0 += __shfl_xor(a0, off, 64);
        a1 += __shfl_xor(a1, off, 64);
        a2 += __shfl_xor(a2, off, 64);
        a3 += __shfl_xor(a3, off, 64);
        wsum += __shfl_xor(wsum, off, 64);
    }
    float inv = 1.0f / wsum;
    float4 bb = ((const float4*)b2)[cq];
    float o0 = a0 * inv + bb.x;
    float o1 = a1 * inv + bb.y;
    float o2 = a2 * inv + bb.z;
    float o3 = a3 * inv + bb.w;
    // log_softmax over 16 cols held as 4 lanes (cq) x 4 cols
    float mx = fmaxf(fmaxf(o0, o1), fmaxf(o2, o3));
    mx = fmaxf(mx, __shfl_xor(mx, 1, 64));
    mx = fmaxf(mx, __shfl_xor(mx, 2, 64));
    float s = __expf(o0 - mx) + __expf(o1 - mx) + __expf(o2 - mx) + __expf(o3 - mx);
    s += __shfl_xor(s, 1, 64);
    s += __shfl_xor(s, 2, 64);
    float l = mx + __logf(s);
    if (slot == 0) {
        float4 r;
        r.x = o0 - l;
        r.y = o1 - l;
        r.z = o2 - l;
        r.w = o3 - l;
        ((float4*)out)[(size_t)v * 4 + cq] = r;
    }
}

// ---------------- launch ----------------

extern "C" void kernel_launch(void* const* d_in, const int* in_sizes, int n_in,
                              void* d_out, int out_size, void* d_ws, size_t ws_size,
                              hipStream_t stream) {
    const float* x = (const float*)d_in[0];
    const int* ei = (const int*)d_in[1];
    const float* W1 = (const float*)d_in[2];
    const float* asrc1 = (const float*)d_in[3];
    const float* adst1 = (const float*)d_in[4];
    const float* b1 = (const float*)d_in[5];
    const float* W2 = (const float*)d_in[6];
    const float* asrc2 = (const float*)d_in[7];
    const float* adst2 = (const float*)d_in[8];
    const float* b2 = (const float*)d_in[9];
    float* out = (float*)d_out;

    int n = in_sizes[0] / 256;   // 50000
    int E = in_sizes[1] / 2;     // 800000
    int P = E + n;
    const int* src = ei;
    const int* dst = ei + E;
    int NB = (n + 255) / 256;

    char* p = (char*)d_ws;
    auto alloc = [&](size_t bytes) {
        void* r = (void*)p;
        p += (bytes + 255) & ~(size_t)255;
        return r;
    };
    unsigned short* h1b = (unsigned short*)alloc((size_t)n * 256 * 2);
    unsigned short* x2b = (unsigned short*)alloc((size_t)n * 256 * 2);
    unsigned short* W1t = (unsigned short*)alloc((size_t)256 * 256 * 2);
    unsigned short* W2t = (unsigned short*)alloc((size_t)16 * 256 * 2);
    float* als1 = (float*)alloc((size_t)n * 8 * 4);
    float* ald1 = (float*)alloc((size_t)n * 8 * 4);
    unsigned short* h2b = (unsigned short*)alloc((size_t)n * 16 * 2);
    float* als2 = (float*)alloc((size_t)n * 4);
    float* ald2 = (float*)alloc((size_t)n * 4);
    int* deg = (int*)alloc((size_t)n * 4);
    int* offs = (int*)alloc((size_t)(n + 1) * 4);
    int* cursor = (int*)alloc((size_t)n * 4);
    int* stmp = (int*)alloc((size_t)n * 4);
    int* blocksum = (int*)alloc((size_t)NB * 4);
    int* blockpre = (int*)alloc((size_t)NB * 4);
    int* csr = (int*)alloc((size_t)P * 4);

    // CSR build
    hipMemsetAsync(deg, 0, (size_t)n * 4, stream);
    k_hist<<<(E + 255) / 256, 256, 0, stream>>>(dst, deg, E);
    k_scanA<<<NB, 256, 0, stream>>>(deg, stmp, blocksum, n);
    k_scanB<<<1, 256, 0, stream>>>(blocksum, blockpre, NB);
    k_scanC<<<NB, 256, 0, stream>>>(stmp, blockpre, offs, cursor, n, P);
    k_scatter<<<(P + 255) / 256, 256, 0, stream>>>(src, dst, cursor, csr, E, n);

    // layer 1
    k_prepw<<<272, 256, 0, stream>>>(W1, W2, W1t, W2t);
    k_gemm1<<<dim3((n + 127) / 128, 2), 256, 0, stream>>>(x, W1t, h1b, n);
    k_al1<<<(n + 3) / 4, 256, 0, stream>>>(h1b, asrc1, adst1, als1, ald1, n);
    k_agg1<<<(n + 3) / 4, 256, 0, stream>>>(csr, offs, als1, ald1, h1b, b1, x2b, n);

    // layer 2
    k_gemm2<<<(n + 63) / 64, 256, 0, stream>>>(x2b, W2t, asrc2, adst2, h2b, als2, ald2, n);
    k_agg2<<<(n + 3) / 4, 256, 0, stream>>>(csr, offs, als2, ald2, h2b, b2, out, n);
}

// Round 7
// 286.349 us; speedup vs baseline: 1.4194x; 1.1433x over previous
//
#include <hip/hip_runtime.h>
#include <hip/hip_bf16.h>

// GATNet v14: k_agg1 declared at its layout roofline (5 structures, all
// 67.4-67.7us, FETCH 222MB — random-gather service-rate bound). This round
// shaves the serial pipeline around it:
//  - k_al1 fused into k_gemm1's epilogue (heads never straddle a column
//    block; als/ald from fp32 accumulators, width-16 shfl reduce) — saves
//    a 25.6MB h1b re-read + 1 launch.
//  - k_scatter de-atomized: k_hist's atomicAdd return value is the row
//    position (pos[i]); scatter is pure writes, self-loop at offs[v+1]-1.
//  - cursor array deleted.

#define LRELU(x) ((x) > 0.f ? (x) : 0.2f * (x))

typedef __attribute__((ext_vector_type(8))) short short8;
typedef __attribute__((ext_vector_type(8))) unsigned short ushort8;
typedef __attribute__((ext_vector_type(4))) float f32x4;

__device__ inline unsigned short f2b(float f) {
    __hip_bfloat16 h = __float2bfloat16(f);
    return *reinterpret_cast<unsigned short*>(&h);
}
__device__ inline float b2f(unsigned short u) {
    __hip_bfloat16 h;
    *reinterpret_cast<unsigned short*>(&h) = u;
    return __bfloat162float(h);
}
__device__ inline float bl(unsigned int u) { return __uint_as_float(u << 16); }
__device__ inline float bh(unsigned int u) { return __uint_as_float(u & 0xffff0000u); }

// ---------------- CSR build ----------------

__global__ void k_hist(const int* __restrict__ dst, int* deg, int* __restrict__ pos, int E) {
    int i = blockIdx.x * blockDim.x + threadIdx.x;
    if (i < E) pos[i] = atomicAdd(&deg[dst[i]], 1);
}

__global__ __launch_bounds__(256) void k_scanA(const int* __restrict__ deg,
                                               int* __restrict__ tmp,
                                               int* __restrict__ blocksum, int n) {
    __shared__ int sc[256];
    int b = blockIdx.x, t = threadIdx.x;
    int i = b * 256 + t;
    int v = (i < n) ? deg[i] + 1 : 0;   // +1: self loop
    sc[t] = v;
    __syncthreads();
    for (int off = 1; off < 256; off <<= 1) {
        int x = 0;
        if (t >= off) x = sc[t - off];
        __syncthreads();
        sc[t] += x;
        __syncthreads();
    }
    if (i < n) tmp[i] = sc[t] - v;
    if (t == 255) blocksum[b] = sc[255];
}

__global__ __launch_bounds__(256) void k_scanB(const int* __restrict__ blocksum,
                                               int* __restrict__ blockpre, int nb) {
    __shared__ int sc[256];
    int t = threadIdx.x;
    int v = (t < nb) ? blocksum[t] : 0;
    sc[t] = v;
    __syncthreads();
    for (int off = 1; off < 256; off <<= 1) {
        int x = 0;
        if (t >= off) x = sc[t - off];
        __syncthreads();
        sc[t] += x;
        __syncthreads();
    }
    if (t < nb) blockpre[t] = sc[t] - v;
}

__global__ __launch_bounds__(256) void k_scanC(const int* __restrict__ tmp,
                                               const int* __restrict__ blockpre,
                                               int* __restrict__ offs, int n, int P) {
    int b = blockIdx.x, t = threadIdx.x;
    int i = b * 256 + t;
    if (i < n) offs[i] = tmp[i] + blockpre[b];
    if (i == 0) offs[n] = P;
}

__global__ void k_scatter(const int* __restrict__ src, const int* __restrict__ dst,
                          const int* __restrict__ pos, const int* __restrict__ offs,
                          int* __restrict__ csr, int E, int n) {
    int i = blockIdx.x * blockDim.x + threadIdx.x;
    if (i < E) {
        int d = dst[i];
        csr[offs[d] + pos[i]] = src[i];
    } else if (i < E + n) {
        int v = i - E;
        csr[offs[v + 1] - 1] = v;   // self loop in the last slot of row v
    }
}

// ---------------- weight prep: W1t[256][256], W2t[16][256] bf16 (merged) ----

__global__ __launch_bounds__(256) void k_prepw(const float* __restrict__ W1,
                                               const float* __restrict__ W2,
                                               unsigned short* __restrict__ W1t,
                                               unsigned short* __restrict__ W2t) {
    int b = blockIdx.x;
    if (b < 256) {
        int k = b, nn = threadIdx.x;
        W1t[nn * 256 + k] = f2b(W1[k * 256 + nn]);
    } else {
        int nn = b - 256, k = threadIdx.x;
        W2t[nn * 256 + k] = f2b(W2[k * 16 + nn]);
    }
}

// ---------------- GEMM1 (MFMA bf16) + fused layer-1 attention logits --------
// 128x128 tile (v10 structure). Epilogue additionally computes als/ald from
// the fp32 accumulators: each wave's 64-col span covers exactly 2 heads
// (head = col>>5), reduced over lane15 via width-16 shfl. Replaces k_al1.

__global__ __launch_bounds__(256) void k_gemm1(const float* __restrict__ A,
                                               const unsigned short* __restrict__ Wt,
                                               const float* __restrict__ asrc,
                                               const float* __restrict__ adst,
                                               unsigned short* __restrict__ h1b,
                                               float* __restrict__ als,
                                               float* __restrict__ ald, int M) {
    __shared__ unsigned short As[128][40];
    __shared__ unsigned short Bs[128][40];
    int t = threadIdx.x;
    int r0 = blockIdx.x * 128, c0 = blockIdx.y * 128;
    int srow = t >> 1, shalf = t & 1;
    int lane = t & 63, w = t >> 6;
    int lane15 = lane & 15, quad = lane >> 4;
    int rbw = (w & 1) * 64, cbw = (w >> 1) * 64;

    f32x4 acc[4][4];
#pragma unroll
    for (int i = 0; i < 4; i++)
#pragma unroll
        for (int j = 0; j < 4; j++) acc[i][j] = (f32x4)0.f;

    for (int k0 = 0; k0 < 256; k0 += 32) {
        {
            int row = r0 + srow;
            ushort8 p0, p1;
            if (row < M) {
                const float4* sp = (const float4*)&A[(size_t)row * 256 + k0 + shalf * 16];
                float4 f0 = sp[0], f1 = sp[1], f2 = sp[2], f3 = sp[3];
                p0[0] = f2b(f0.x); p0[1] = f2b(f0.y); p0[2] = f2b(f0.z); p0[3] = f2b(f0.w);
                p0[4] = f2b(f1.x); p0[5] = f2b(f1.y); p0[6] = f2b(f1.z); p0[7] = f2b(f1.w);
                p1[0] = f2b(f2.x); p1[1] = f2b(f2.y); p1[2] = f2b(f2.z); p1[3] = f2b(f2.w);
                p1[4] = f2b(f3.x); p1[5] = f2b(f3.y); p1[6] = f2b(f3.z); p1[7] = f2b(f3.w);
            } else {
                p0 = (ushort8)0; p1 = (ushort8)0;
            }
            *(ushort8*)&As[srow][shalf * 16] = p0;
            *(ushort8*)&As[srow][shalf * 16 + 8] = p1;
            const ushort8* bp = (const ushort8*)&Wt[(size_t)(c0 + srow) * 256 + k0 + shalf * 16];
            *(ushort8*)&Bs[srow][shalf * 16] = bp[0];
            *(ushort8*)&Bs[srow][shalf * 16 + 8] = bp[1];
        }
        __syncthreads();
        short8 af[4], bf[4];
#pragma unroll
        for (int i = 0; i < 4; i++)
            af[i] = *(const short8*)&As[rbw + i * 16 + lane15][quad * 8];
#pragma unroll
        for (int j = 0; j < 4; j++)
            bf[j] = *(const short8*)&Bs[cbw + j * 16 + lane15][quad * 8];
#pragma unroll
        for (int i = 0; i < 4; i++)
#pragma unroll
            for (int j = 0; j < 4; j++)
                acc[i][j] = __builtin_amdgcn_mfma_f32_16x16x32_bf16(af[i], bf[j], acc[i][j], 0, 0, 0);
        __syncthreads();
    }
    // h1b store
#pragma unroll
    for (int i = 0; i < 4; i++) {
        int rowb = r0 + rbw + i * 16 + quad * 4;
#pragma unroll
        for (int j = 0; j < 4; j++) {
            int col = c0 + cbw + j * 16 + lane15;
#pragma unroll
            for (int r = 0; r < 4; r++) {
                int row = rowb + r;
                if (row < M) h1b[(size_t)row * 256 + col] = f2b(acc[i][j][r]);
            }
        }
    }
    // fused attention logits (replaces k_al1): 2 heads per wave-col-span
    float asv[4], adv[4];
#pragma unroll
    for (int j = 0; j < 4; j++) {
        asv[j] = asrc[c0 + cbw + j * 16 + lane15];
        adv[j] = adst[c0 + cbw + j * 16 + lane15];
    }
    int hbase = (c0 + cbw) >> 5;
#pragma unroll
    for (int i = 0; i < 4; i++) {
#pragma unroll
        for (int r = 0; r < 4; r++) {
            int row = r0 + rbw + i * 16 + quad * 4 + r;
            float ps0 = acc[i][0][r] * asv[0] + acc[i][1][r] * asv[1];
            float pd0 = acc[i][0][r] * adv[0] + acc[i][1][r] * adv[1];
            float ps1 = acc[i][2][r] * asv[2] + acc[i][3][r] * asv[3];
            float pd1 = acc[i][2][r] * adv[2] + acc[i][3][r] * adv[3];
#pragma unroll
            for (int off = 1; off < 16; off <<= 1) {
                ps0 += __shfl_xor(ps0, off, 16);
                pd0 += __shfl_xor(pd0, off, 16);
                ps1 += __shfl_xor(ps1, off, 16);
                pd1 += __shfl_xor(pd1, off, 16);
            }
            if (lane15 == 0 && row < M) {
                als[(size_t)row * 8 + hbase] = ps0;
                ald[(size_t)row * 8 + hbase] = pd0;
                als[(size_t)row * 8 + hbase + 1] = ps1;
                ald[(size_t)row * 8 + hbase + 1] = pd1;
            }
        }
    }
}

// ---------------- layer-1 aggregate: self-service weights, no LDS/fences ----
// (v13 structure — at the random-gather service-rate roofline, ~67.5us)

__global__ __launch_bounds__(256) void k_agg1(const int* __restrict__ csr,
                                              const int* __restrict__ offs,
                                              const float* __restrict__ als,
                                              const float* __restrict__ aldg,
                                              const unsigned short* __restrict__ h1b,
                                              const float* __restrict__ b1,
                                              unsigned short* __restrict__ x2b, int n) {
    int wid = threadIdx.x >> 6;
    int v = blockIdx.x * 4 + wid;
    if (v >= n) return;
    int lane = threadIdx.x & 63;
    int h = lane >> 3;
    int start = __builtin_amdgcn_readfirstlane(offs[v]);
    int deg = __builtin_amdgcn_readfirstlane(offs[v + 1]) - start;
    const int* __restrict__ cp = csr + start;
    int dm1 = deg - 1;
    float aldvh = aldg[(size_t)v * 8 + h];
    float a0 = 0.f, a1 = 0.f, a2 = 0.f, a3 = 0.f, wsum = 0.f;
    for (int e = 0; e < deg; e += 4) {
        int u0 = cp[e];                  // e < deg always
        int u1 = cp[min(e + 1, dm1)];
        int u2 = cp[min(e + 2, dm1)];
        int u3 = cp[min(e + 3, dm1)];
        uint2 p0 = ((const uint2*)(h1b + (size_t)u0 * 256))[lane];
        uint2 p1 = ((const uint2*)(h1b + (size_t)u1 * 256))[lane];
        uint2 p2 = ((const uint2*)(h1b + (size_t)u2 * 256))[lane];
        uint2 p3 = ((const uint2*)(h1b + (size_t)u3 * 256))[lane];
        float x0 = als[u0 * 8 + h];
        float x1 = als[u1 * 8 + h];
        float x2 = als[u2 * 8 + h];
        float x3 = als[u3 * 8 + h];
        float w0 = __expf(LRELU(x0 + aldvh));
        float w1 = __expf(LRELU(x1 + aldvh));
        float w2 = __expf(LRELU(x2 + aldvh));
        float w3 = __expf(LRELU(x3 + aldvh));
        if (e + 1 > dm1) w1 = 0.f;
        if (e + 2 > dm1) w2 = 0.f;
        if (e + 3 > dm1) w3 = 0.f;
        a0 += w0 * bl(p0.x); a1 += w0 * bh(p0.x);
        a2 += w0 * bl(p0.y); a3 += w0 * bh(p0.y);
        a0 += w1 * bl(p1.x); a1 += w1 * bh(p1.x);
        a2 += w1 * bl(p1.y); a3 += w1 * bh(p1.y);
        a0 += w2 * bl(p2.x); a1 += w2 * bh(p2.x);
        a2 += w2 * bl(p2.y); a3 += w2 * bh(p2.y);
        a0 += w3 * bl(p3.x); a1 += w3 * bh(p3.x);
        a2 += w3 * bl(p3.y); a3 += w3 * bh(p3.y);
        wsum += (w0 + w1) + (w2 + w3);
    }
    float inv = 1.0f / wsum;
    float4 bb = ((const float4*)b1)[lane];
    float o0 = fmaxf(a0 * inv + bb.x, 0.f);
    float o1 = fmaxf(a1 * inv + bb.y, 0.f);
    float o2 = fmaxf(a2 * inv + bb.z, 0.f);
    float o3 = fmaxf(a3 * inv + bb.w, 0.f);
    uint2 o;
    o.x = (unsigned int)f2b(o0) | ((unsigned int)f2b(o1) << 16);
    o.y = (unsigned int)f2b(o2) | ((unsigned int)f2b(o3) << 16);
    ((uint2*)(x2b + (size_t)v * 256))[lane] = o;
}

// ---------------- GEMM2 (MFMA) + fused layer-2 logits ----------------------

__global__ __launch_bounds__(256) void k_gemm2(const unsigned short* __restrict__ Xb,
                                               const unsigned short* __restrict__ W2t,
                                               const float* __restrict__ asrc,
                                               const float* __restrict__ adst,
                                               unsigned short* __restrict__ h2b,
                                               float* __restrict__ als,
                                               float* __restrict__ ald, int n) {
    int t = threadIdx.x;
    int lane = t & 63, w = t >> 6;
    int lane15 = lane & 15, quad = lane >> 4;
    int row0 = blockIdx.x * 64 + w * 16;
    f32x4 acc = (f32x4)0.f;
#pragma unroll
    for (int k0 = 0; k0 < 256; k0 += 32) {
        short8 a = *(const short8*)&Xb[(size_t)(row0 + lane15) * 256 + k0 + quad * 8];
        short8 b = *(const short8*)&W2t[lane15 * 256 + k0 + quad * 8];
        acc = __builtin_amdgcn_mfma_f32_16x16x32_bf16(a, b, acc, 0, 0, 0);
    }
    float asv = asrc[lane15], adv = adst[lane15];
#pragma unroll
    for (int r = 0; r < 4; r++) {
        int row = row0 + quad * 4 + r;
        float hv = acc[r];
        float ps = hv * asv, pd = hv * adv;
#pragma unroll
        for (int off = 1; off < 16; off <<= 1) {
            ps += __shfl_xor(ps, off, 16);
            pd += __shfl_xor(pd, off, 16);
        }
        if (row < n) {
            h2b[(size_t)row * 16 + lane15] = f2b(hv);
            if (lane15 == 0) {
                als[row] = ps;
                ald[row] = pd;
            }
        }
    }
}

// ---------------- layer-2 aggregate: self-service weights + log_softmax -----

__global__ __launch_bounds__(256) void k_agg2(const int* __restrict__ csr,
                                              const int* __restrict__ offs,
                                              const float* __restrict__ als,
                                              const float* __restrict__ aldg,
                                              const unsigned short* __restrict__ h2b,
                                              const float* __restrict__ b2,
                                              float* __restrict__ out, int n) {
    int wid = threadIdx.x >> 6;
    int v = blockIdx.x * 4 + wid;
    if (v >= n) return;
    int lane = threadIdx.x & 63;
    int slot = lane >> 2, cq = lane & 3;
    int start = __builtin_amdgcn_readfirstlane(offs[v]);
    int deg = __builtin_amdgcn_readfirstlane(offs[v + 1]) - start;
    int dm1 = deg - 1;
    float aldv = aldg[v];
    float a0 = 0.f, a1 = 0.f, a2 = 0.f, a3 = 0.f, wsum = 0.f;
    for (int e = 0; e < deg; e += 32) {
        int iA = min(e + slot, dm1);
        int iB = min(e + 16 + slot, dm1);
        int uA = csr[start + iA];
        int uB = csr[start + iB];
        uint2 pA = ((const uint2*)(h2b + (size_t)uA * 16))[cq];
        uint2 pB = ((const uint2*)(h2b + (size_t)uB * 16))[cq];
        float xA = als[uA] + aldv;
        float xB = als[uB] + aldv;
        float wA = __expf(LRELU(xA));
        float wB = __expf(LRELU(xB));
        if (e + slot > dm1) wA = 0.f;
        if (e + 16 + slot > dm1) wB = 0.f;
        a0 += wA * bl(pA.x) + wB * bl(pB.x);
        a1 += wA * bh(pA.x) + wB * bh(pB.x);
        a2 += wA * bl(pA.y) + wB * bl(pB.y);
        a3 += wA * bh(pA.y) + wB * bh(pB.y);
        wsum += wA + wB;
    }
    // reduce over 16 edge slots (lane bits 2..5)
#pragma unroll
    for (int off = 4; off < 64; off <<= 1) {
        a0 += __shfl_xor(a0, off, 64);
        a1 += __shfl_xor(a1, off, 64);
        a2 += __shfl_xor(a2, off, 64);
        a3 += __shfl_xor(a3, off, 64);
        wsum += __shfl_xor(wsum, off, 64);
    }
    float inv = 1.0f / wsum;
    float4 bb = ((const float4*)b2)[cq];
    float o0 = a0 * inv + bb.x;
    float o1 = a1 * inv + bb.y;
    float o2 = a2 * inv + bb.z;
    float o3 = a3 * inv + bb.w;
    // log_softmax over 16 cols held as 4 lanes (cq) x 4 cols
    float mx = fmaxf(fmaxf(o0, o1), fmaxf(o2, o3));
    mx = fmaxf(mx, __shfl_xor(mx, 1, 64));
    mx = fmaxf(mx, __shfl_xor(mx, 2, 64));
    float s = __expf(o0 - mx) + __expf(o1 - mx) + __expf(o2 - mx) + __expf(o3 - mx);
    s += __shfl_xor(s, 1, 64);
    s += __shfl_xor(s, 2, 64);
    float l = mx + __logf(s);
    if (slot == 0) {
        float4 r;
        r.x = o0 - l;
        r.y = o1 - l;
        r.z = o2 - l;
        r.w = o3 - l;
        ((float4*)out)[(size_t)v * 4 + cq] = r;
    }
}

// ---------------- launch ----------------

extern "C" void kernel_launch(void* const* d_in, const int* in_sizes, int n_in,
                              void* d_out, int out_size, void* d_ws, size_t ws_size,
                              hipStream_t stream) {
    const float* x = (const float*)d_in[0];
    const int* ei = (const int*)d_in[1];
    const float* W1 = (const float*)d_in[2];
    const float* asrc1 = (const float*)d_in[3];
    const float* adst1 = (const float*)d_in[4];
    const float* b1 = (const float*)d_in[5];
    const float* W2 = (const float*)d_in[6];
    const float* asrc2 = (const float*)d_in[7];
    const float* adst2 = (const float*)d_in[8];
    const float* b2 = (const float*)d_in[9];
    float* out = (float*)d_out;

    int n = in_sizes[0] / 256;   // 50000
    int E = in_sizes[1] / 2;     // 800000
    int P = E + n;
    const int* src = ei;
    const int* dst = ei + E;
    int NB = (n + 255) / 256;

    char* p = (char*)d_ws;
    auto alloc = [&](size_t bytes) {
        void* r = (void*)p;
        p += (bytes + 255) & ~(size_t)255;
        return r;
    };
    unsigned short* h1b = (unsigned short*)alloc((size_t)n * 256 * 2);
    unsigned short* x2b = (unsigned short*)alloc((size_t)n * 256 * 2);
    unsigned short* W1t = (unsigned short*)alloc((size_t)256 * 256 * 2);
    unsigned short* W2t = (unsigned short*)alloc((size_t)16 * 256 * 2);
    float* als1 = (float*)alloc((size_t)n * 8 * 4);
    float* ald1 = (float*)alloc((size_t)n * 8 * 4);
    unsigned short* h2b = (unsigned short*)alloc((size_t)n * 16 * 2);
    float* als2 = (float*)alloc((size_t)n * 4);
    float* ald2 = (float*)alloc((size_t)n * 4);
    int* deg = (int*)alloc((size_t)n * 4);
    int* offs = (int*)alloc((size_t)(n + 1) * 4);
    int* pos = (int*)alloc((size_t)E * 4);
    int* stmp = (int*)alloc((size_t)n * 4);
    int* blocksum = (int*)alloc((size_t)NB * 4);
    int* blockpre = (int*)alloc((size_t)NB * 4);
    int* csr = (int*)alloc((size_t)P * 4);

    // CSR build (scatter is atomic-free: hist records per-edge row position)
    hipMemsetAsync(deg, 0, (size_t)n * 4, stream);
    k_hist<<<(E + 255) / 256, 256, 0, stream>>>(dst, deg, pos, E);
    k_scanA<<<NB, 256, 0, stream>>>(deg, stmp, blocksum, n);
    k_scanB<<<1, 256, 0, stream>>>(blocksum, blockpre, NB);
    k_scanC<<<NB, 256, 0, stream>>>(stmp, blockpre, offs, n, P);
    k_scatter<<<(P + 255) / 256, 256, 0, stream>>>(src, dst, pos, offs, csr, E, n);

    // layer 1 (gemm1 fuses attention logits; k_al1 eliminated)
    k_prepw<<<272, 256, 0, stream>>>(W1, W2, W1t, W2t);
    k_gemm1<<<dim3((n + 127) / 128, 2), 256, 0, stream>>>(x, W1t, asrc1, adst1, h1b, als1, ald1, n);
    k_agg1<<<(n + 3) / 4, 256, 0, stream>>>(csr, offs, als1, ald1, h1b, b1, x2b, n);

    // layer 2
    k_gemm2<<<(n + 63) / 64, 256, 0, stream>>>(x2b, W2t, asrc2, adst2, h2b, als2, ald2, n);
    k_agg2<<<(n + 3) / 4, 256, 0, stream>>>(csr, offs, als2, ald2, h2b, b2, out, n);
}

// Round 8
// 284.206 us; speedup vs baseline: 1.4301x; 1.0075x over previous
//
#include <hip/hip_runtime.h>
#include <hip/hip_bf16.h>

// GATNet v15: dispatch-count reduction 11 -> 8. v14's overshoot (-41us for
// ~20us of removed work) implies large inter-kernel overhead. Changes:
//  - scanA/B/C fused into one kernel (196 co-resident blocks; single-word
//    flag|aggregate publish via atomicExch, per-block predecessor spin +
//    LDS tree reduce -> prefix). State zeroed by the existing memset.
//  - k_prepw merged into k_scatter (independent work, blockIdx branch).
//  - k_agg1 (67.4us, FETCH 222MB) at its random-gather service roofline:
//    5 structures all 67.4-67.7us; left untouched (v13 structure).

#define LRELU(x) ((x) > 0.f ? (x) : 0.2f * (x))

typedef __attribute__((ext_vector_type(8))) short short8;
typedef __attribute__((ext_vector_type(8))) unsigned short ushort8;
typedef __attribute__((ext_vector_type(4))) float f32x4;

__device__ inline unsigned short f2b(float f) {
    __hip_bfloat16 h = __float2bfloat16(f);
    return *reinterpret_cast<unsigned short*>(&h);
}
__device__ inline float b2f(unsigned short u) {
    __hip_bfloat16 h;
    *reinterpret_cast<unsigned short*>(&h) = u;
    return __bfloat162float(h);
}
__device__ inline float bl(unsigned int u) { return __uint_as_float(u << 16); }
__device__ inline float bh(unsigned int u) { return __uint_as_float(u & 0xffff0000u); }

// ---------------- CSR build ----------------

__global__ void k_hist(const int* __restrict__ dst, int* deg, int* __restrict__ pos, int E) {
    int i = blockIdx.x * blockDim.x + threadIdx.x;
    if (i < E) pos[i] = atomicAdd(&deg[dst[i]], 1);
}

// Fused 3-phase scan in one kernel. Grid = NB (196) blocks, all co-resident
// (grid < 256 CUs). Block b: local inclusive scan; publish aggregate with
// flag bit in ONE 32-bit word (no fence protocol needed); threads t<b spin
// for predecessor t's word; tree-reduce -> prefix; write offs.
__global__ __launch_bounds__(256) void k_scan(const int* __restrict__ deg,
                                              unsigned int* __restrict__ state,
                                              int* __restrict__ offs, int n, int P) {
    __shared__ int sc[256];
    __shared__ int sa[256];
    int b = blockIdx.x, t = threadIdx.x;
    int i = b * 256 + t;
    int v = (i < n) ? deg[i] + 1 : 0;   // +1: self loop
    sc[t] = v;
    __syncthreads();
    for (int off = 1; off < 256; off <<= 1) {
        int x = 0;
        if (t >= off) x = sc[t - off];
        __syncthreads();
        sc[t] += x;
        __syncthreads();
    }
    if (t == 255) {
        unsigned int pack = 0x80000000u | (unsigned int)sc[255];
        atomicExch(&state[b], pack);   // device-scope publish (flag+value, one word)
    }
    // gather predecessor aggregates (each thread spins on at most one)
    if (t < b) {
        unsigned int s;
        do {
            s = atomicAdd(&state[t], 0u);   // device-scope read
        } while (!(s & 0x80000000u));
        sa[t] = (int)(s & 0x7fffffffu);
    } else {
        sa[t] = 0;
    }
    __syncthreads();
    for (int off = 128; off; off >>= 1) {
        if (t < off) sa[t] += sa[t + off];
        __syncthreads();
    }
    int prefix = sa[0];
    if (i < n) offs[i] = prefix + sc[t] - v;   // exclusive
    if (i == 0) offs[n] = P;
}

// scatter (atomic-free via pos) + weight prep merged (independent work).
// scatter blocks: [0, SB); prepw blocks: [SB, SB+272).
__global__ void k_scatter(const int* __restrict__ src, const int* __restrict__ dst,
                          const int* __restrict__ pos, const int* __restrict__ offs,
                          int* __restrict__ csr,
                          const float* __restrict__ W1, const float* __restrict__ W2,
                          unsigned short* __restrict__ W1t, unsigned short* __restrict__ W2t,
                          int E, int n, int SB) {
    int b = blockIdx.x;
    if (b < SB) {
        int i = b * blockDim.x + threadIdx.x;
        if (i < E) {
            int d = dst[i];
            csr[offs[d] + pos[i]] = src[i];
        } else if (i < E + n) {
            int v = i - E;
            csr[offs[v + 1] - 1] = v;   // self loop in the last slot of row v
        }
    } else {
        int bb = b - SB;
        if (bb < 256) {
            int k = bb, nn = threadIdx.x;
            W1t[nn * 256 + k] = f2b(W1[k * 256 + nn]);
        } else {
            int nn = bb - 256, k = threadIdx.x;
            W2t[nn * 256 + k] = f2b(W2[k * 16 + nn]);
        }
    }
}

// ---------------- GEMM1 (MFMA bf16) + fused layer-1 attention logits --------
// 128x128 tile. Epilogue computes als/ald from fp32 accumulators (each
// wave's 64-col span = exactly 2 heads), width-16 shfl reduce.

__global__ __launch_bounds__(256) void k_gemm1(const float* __restrict__ A,
                                               const unsigned short* __restrict__ Wt,
                                               const float* __restrict__ asrc,
                                               const float* __restrict__ adst,
                                               unsigned short* __restrict__ h1b,
                                               float* __restrict__ als,
                                               float* __restrict__ ald, int M) {
    __shared__ unsigned short As[128][40];
    __shared__ unsigned short Bs[128][40];
    int t = threadIdx.x;
    int r0 = blockIdx.x * 128, c0 = blockIdx.y * 128;
    int srow = t >> 1, shalf = t & 1;
    int lane = t & 63, w = t >> 6;
    int lane15 = lane & 15, quad = lane >> 4;
    int rbw = (w & 1) * 64, cbw = (w >> 1) * 64;

    f32x4 acc[4][4];
#pragma unroll
    for (int i = 0; i < 4; i++)
#pragma unroll
        for (int j = 0; j < 4; j++) acc[i][j] = (f32x4)0.f;

    for (int k0 = 0; k0 < 256; k0 += 32) {
        {
            int row = r0 + srow;
            ushort8 p0, p1;
            if (row < M) {
                const float4* sp = (const float4*)&A[(size_t)row * 256 + k0 + shalf * 16];
                float4 f0 = sp[0], f1 = sp[1], f2 = sp[2], f3 = sp[3];
                p0[0] = f2b(f0.x); p0[1] = f2b(f0.y); p0[2] = f2b(f0.z); p0[3] = f2b(f0.w);
                p0[4] = f2b(f1.x); p0[5] = f2b(f1.y); p0[6] = f2b(f1.z); p0[7] = f2b(f1.w);
                p1[0] = f2b(f2.x); p1[1] = f2b(f2.y); p1[2] = f2b(f2.z); p1[3] = f2b(f2.w);
                p1[4] = f2b(f3.x); p1[5] = f2b(f3.y); p1[6] = f2b(f3.z); p1[7] = f2b(f3.w);
            } else {
                p0 = (ushort8)0; p1 = (ushort8)0;
            }
            *(ushort8*)&As[srow][shalf * 16] = p0;
            *(ushort8*)&As[srow][shalf * 16 + 8] = p1;
            const ushort8* bp = (const ushort8*)&Wt[(size_t)(c0 + srow) * 256 + k0 + shalf * 16];
            *(ushort8*)&Bs[srow][shalf * 16] = bp[0];
            *(ushort8*)&Bs[srow][shalf * 16 + 8] = bp[1];
        }
        __syncthreads();
        short8 af[4], bf[4];
#pragma unroll
        for (int i = 0; i < 4; i++)
            af[i] = *(const short8*)&As[rbw + i * 16 + lane15][quad * 8];
#pragma unroll
        for (int j = 0; j < 4; j++)
            bf[j] = *(const short8*)&Bs[cbw + j * 16 + lane15][quad * 8];
#pragma unroll
        for (int i = 0; i < 4; i++)
#pragma unroll
            for (int j = 0; j < 4; j++)
                acc[i][j] = __builtin_amdgcn_mfma_f32_16x16x32_bf16(af[i], bf[j], acc[i][j], 0, 0, 0);
        __syncthreads();
    }
    // h1b store
#pragma unroll
    for (int i = 0; i < 4; i++) {
        int rowb = r0 + rbw + i * 16 + quad * 4;
#pragma unroll
        for (int j = 0; j < 4; j++) {
            int col = c0 + cbw + j * 16 + lane15;
#pragma unroll
            for (int r = 0; r < 4; r++) {
                int row = rowb + r;
                if (row < M) h1b[(size_t)row * 256 + col] = f2b(acc[i][j][r]);
            }
        }
    }
    // fused attention logits (replaces k_al1): 2 heads per wave-col-span
    float asv[4], adv[4];
#pragma unroll
    for (int j = 0; j < 4; j++) {
        asv[j] = asrc[c0 + cbw + j * 16 + lane15];
        adv[j] = adst[c0 + cbw + j * 16 + lane15];
    }
    int hbase = (c0 + cbw) >> 5;
#pragma unroll
    for (int i = 0; i < 4; i++) {
#pragma unroll
        for (int r = 0; r < 4; r++) {
            int row = r0 + rbw + i * 16 + quad * 4 + r;
            float ps0 = acc[i][0][r] * asv[0] + acc[i][1][r] * asv[1];
            float pd0 = acc[i][0][r] * adv[0] + acc[i][1][r] * adv[1];
            float ps1 = acc[i][2][r] * asv[2] + acc[i][3][r] * asv[3];
            float pd1 = acc[i][2][r] * adv[2] + acc[i][3][r] * adv[3];
#pragma unroll
            for (int off = 1; off < 16; off <<= 1) {
                ps0 += __shfl_xor(ps0, off, 16);
                pd0 += __shfl_xor(pd0, off, 16);
                ps1 += __shfl_xor(ps1, off, 16);
                pd1 += __shfl_xor(pd1, off, 16);
            }
            if (lane15 == 0 && row < M) {
                als[(size_t)row * 8 + hbase] = ps0;
                ald[(size_t)row * 8 + hbase] = pd0;
                als[(size_t)row * 8 + hbase + 1] = ps1;
                ald[(size_t)row * 8 + hbase + 1] = pd1;
            }
        }
    }
}

// ---------------- layer-1 aggregate: self-service weights, no LDS/fences ----
// (v13 structure — at the random-gather service-rate roofline, ~67.5us)

__global__ __launch_bounds__(256) void k_agg1(const int* __restrict__ csr,
                                              const int* __restrict__ offs,
                                              const float* __restrict__ als,
                                              const float* __restrict__ aldg,
                                              const unsigned short* __restrict__ h1b,
                                              const float* __restrict__ b1,
                                              unsigned short* __restrict__ x2b, int n) {
    int wid = threadIdx.x >> 6;
    int v = blockIdx.x * 4 + wid;
    if (v >= n) return;
    int lane = threadIdx.x & 63;
    int h = lane >> 3;
    int start = __builtin_amdgcn_readfirstlane(offs[v]);
    int deg = __builtin_amdgcn_readfirstlane(offs[v + 1]) - start;
    const int* __restrict__ cp = csr + start;
    int dm1 = deg - 1;
    float aldvh = aldg[(size_t)v * 8 + h];
    float a0 = 0.f, a1 = 0.f, a2 = 0.f, a3 = 0.f, wsum = 0.f;
    for (int e = 0; e < deg; e += 4) {
        int u0 = cp[e];                  // e < deg always
        int u1 = cp[min(e + 1, dm1)];
        int u2 = cp[min(e + 2, dm1)];
        int u3 = cp[min(e + 3, dm1)];
        uint2 p0 = ((const uint2*)(h1b + (size_t)u0 * 256))[lane];
        uint2 p1 = ((const uint2*)(h1b + (size_t)u1 * 256))[lane];
        uint2 p2 = ((const uint2*)(h1b + (size_t)u2 * 256))[lane];
        uint2 p3 = ((const uint2*)(h1b + (size_t)u3 * 256))[lane];
        float x0 = als[u0 * 8 + h];
        float x1 = als[u1 * 8 + h];
        float x2 = als[u2 * 8 + h];
        float x3 = als[u3 * 8 + h];
        float w0 = __expf(LRELU(x0 + aldvh));
        float w1 = __expf(LRELU(x1 + aldvh));
        float w2 = __expf(LRELU(x2 + aldvh));
        float w3 = __expf(LRELU(x3 + aldvh));
        if (e + 1 > dm1) w1 = 0.f;
        if (e + 2 > dm1) w2 = 0.f;
        if (e + 3 > dm1) w3 = 0.f;
        a0 += w0 * bl(p0.x); a1 += w0 * bh(p0.x);
        a2 += w0 * bl(p0.y); a3 += w0 * bh(p0.y);
        a0 += w1 * bl(p1.x); a1 += w1 * bh(p1.x);
        a2 += w1 * bl(p1.y); a3 += w1 * bh(p1.y);
        a0 += w2 * bl(p2.x); a1 += w2 * bh(p2.x);
        a2 += w2 * bl(p2.y); a3 += w2 * bh(p2.y);
        a0 += w3 * bl(p3.x); a1 += w3 * bh(p3.x);
        a2 += w3 * bl(p3.y); a3 += w3 * bh(p3.y);
        wsum += (w0 + w1) + (w2 + w3);
    }
    float inv = 1.0f / wsum;
    float4 bb = ((const float4*)b1)[lane];
    float o0 = fmaxf(a0 * inv + bb.x, 0.f);
    float o1 = fmaxf(a1 * inv + bb.y, 0.f);
    float o2 = fmaxf(a2 * inv + bb.z, 0.f);
    float o3 = fmaxf(a3 * inv + bb.w, 0.f);
    uint2 o;
    o.x = (unsigned int)f2b(o0) | ((unsigned int)f2b(o1) << 16);
    o.y = (unsigned int)f2b(o2) | ((unsigned int)f2b(o3) << 16);
    ((uint2*)(x2b + (size_t)v * 256))[lane] = o;
}

// ---------------- GEMM2 (MFMA) + fused layer-2 logits ----------------------

__global__ __launch_bounds__(256) void k_gemm2(const unsigned short* __restrict__ Xb,
                                               const unsigned short* __restrict__ W2t,
                                               const float* __restrict__ asrc,
                                               const float* __restrict__ adst,
                                               unsigned short* __restrict__ h2b,
                                               float* __restrict__ als,
                                               float* __restrict__ ald, int n) {
    int t = threadIdx.x;
    int lane = t & 63, w = t >> 6;
    int lane15 = lane & 15, quad = lane >> 4;
    int row0 = blockIdx.x * 64 + w * 16;
    f32x4 acc = (f32x4)0.f;
#pragma unroll
    for (int k0 = 0; k0 < 256; k0 += 32) {
        short8 a = *(const short8*)&Xb[(size_t)(row0 + lane15) * 256 + k0 + quad * 8];
        short8 b = *(const short8*)&W2t[lane15 * 256 + k0 + quad * 8];
        acc = __builtin_amdgcn_mfma_f32_16x16x32_bf16(a, b, acc, 0, 0, 0);
    }
    float asv = asrc[lane15], adv = adst[lane15];
#pragma unroll
    for (int r = 0; r < 4; r++) {
        int row = row0 + quad * 4 + r;
        float hv = acc[r];
        float ps = hv * asv, pd = hv * adv;
#pragma unroll
        for (int off = 1; off < 16; off <<= 1) {
            ps += __shfl_xor(ps, off, 16);
            pd += __shfl_xor(pd, off, 16);
        }
        if (row < n) {
            h2b[(size_t)row * 16 + lane15] = f2b(hv);
            if (lane15 == 0) {
                als[row] = ps;
                ald[row] = pd;
            }
        }
    }
}

// ---------------- layer-2 aggregate: self-service weights + log_softmax -----

__global__ __launch_bounds__(256) void k_agg2(const int* __restrict__ csr,
                                              const int* __restrict__ offs,
                                              const float* __restrict__ als,
                                              const float* __restrict__ aldg,
                                              const unsigned short* __restrict__ h2b,
                                              const float* __restrict__ b2,
                                              float* __restrict__ out, int n) {
    int wid = threadIdx.x >> 6;
    int v = blockIdx.x * 4 + wid;
    if (v >= n) return;
    int lane = threadIdx.x & 63;
    int slot = lane >> 2, cq = lane & 3;
    int start = __builtin_amdgcn_readfirstlane(offs[v]);
    int deg = __builtin_amdgcn_readfirstlane(offs[v + 1]) - start;
    int dm1 = deg - 1;
    float aldv = aldg[v];
    float a0 = 0.f, a1 = 0.f, a2 = 0.f, a3 = 0.f, wsum = 0.f;
    for (int e = 0; e < deg; e += 32) {
        int iA = min(e + slot, dm1);
        int iB = min(e + 16 + slot, dm1);
        int uA = csr[start + iA];
        int uB = csr[start + iB];
        uint2 pA = ((const uint2*)(h2b + (size_t)uA * 16))[cq];
        uint2 pB = ((const uint2*)(h2b + (size_t)uB * 16))[cq];
        float xA = als[uA] + aldv;
        float xB = als[uB] + aldv;
        float wA = __expf(LRELU(xA));
        float wB = __expf(LRELU(xB));
        if (e + slot > dm1) wA = 0.f;
        if (e + 16 + slot > dm1) wB = 0.f;
        a0 += wA * bl(pA.x) + wB * bl(pB.x);
        a1 += wA * bh(pA.x) + wB * bh(pB.x);
        a2 += wA * bl(pA.y) + wB * bl(pB.y);
        a3 += wA * bh(pA.y) + wB * bh(pB.y);
        wsum += wA + wB;
    }
    // reduce over 16 edge slots (lane bits 2..5)
#pragma unroll
    for (int off = 4; off < 64; off <<= 1) {
        a0 += __shfl_xor(a0, off, 64);
        a1 += __shfl_xor(a1, off, 64);
        a2 += __shfl_xor(a2, off, 64);
        a3 += __shfl_xor(a3, off, 64);
        wsum += __shfl_xor(wsum, off, 64);
    }
    float inv = 1.0f / wsum;
    float4 bb = ((const float4*)b2)[cq];
    float o0 = a0 * inv + bb.x;
    float o1 = a1 * inv + bb.y;
    float o2 = a2 * inv + bb.z;
    float o3 = a3 * inv + bb.w;
    // log_softmax over 16 cols held as 4 lanes (cq) x 4 cols
    float mx = fmaxf(fmaxf(o0, o1), fmaxf(o2, o3));
    mx = fmaxf(mx, __shfl_xor(mx, 1, 64));
    mx = fmaxf(mx, __shfl_xor(mx, 2, 64));
    float s = __expf(o0 - mx) + __expf(o1 - mx) + __expf(o2 - mx) + __expf(o3 - mx);
    s += __shfl_xor(s, 1, 64);
    s += __shfl_xor(s, 2, 64);
    float l = mx + __logf(s);
    if (slot == 0) {
        float4 r;
        r.x = o0 - l;
        r.y = o1 - l;
        r.z = o2 - l;
        r.w = o3 - l;
        ((float4*)out)[(size_t)v * 4 + cq] = r;
    }
}

// ---------------- launch ----------------

extern "C" void kernel_launch(void* const* d_in, const int* in_sizes, int n_in,
                              void* d_out, int out_size, void* d_ws, size_t ws_size,
                              hipStream_t stream) {
    const float* x = (const float*)d_in[0];
    const int* ei = (const int*)d_in[1];
    const float* W1 = (const float*)d_in[2];
    const float* asrc1 = (const float*)d_in[3];
    const float* adst1 = (const float*)d_in[4];
    const float* b1 = (const float*)d_in[5];
    const float* W2 = (const float*)d_in[6];
    const float* asrc2 = (const float*)d_in[7];
    const float* adst2 = (const float*)d_in[8];
    const float* b2 = (const float*)d_in[9];
    float* out = (float*)d_out;

    int n = in_sizes[0] / 256;   // 50000
    int E = in_sizes[1] / 2;     // 800000
    int P = E + n;
    const int* src = ei;
    const int* dst = ei + E;
    int NB = (n + 255) / 256;
    int SB = (P + 255) / 256;    // scatter blocks

    char* p = (char*)d_ws;
    auto alloc = [&](size_t bytes) {
        void* r = (void*)p;
        p += (bytes + 255) & ~(size_t)255;
        return r;
    };
    unsigned short* h1b = (unsigned short*)alloc((size_t)n * 256 * 2);
    unsigned short* x2b = (unsigned short*)alloc((size_t)n * 256 * 2);
    unsigned short* W1t = (unsigned short*)alloc((size_t)256 * 256 * 2);
    unsigned short* W2t = (unsigned short*)alloc((size_t)16 * 256 * 2);
    float* als1 = (float*)alloc((size_t)n * 8 * 4);
    float* ald1 = (float*)alloc((size_t)n * 8 * 4);
    unsigned short* h2b = (unsigned short*)alloc((size_t)n * 16 * 2);
    float* als2 = (float*)alloc((size_t)n * 4);
    float* ald2 = (float*)alloc((size_t)n * 4);
    int* zarea = (int*)alloc((size_t)(n + NB) * 4);   // deg[n] + scan state[NB]
    int* deg = zarea;
    unsigned int* sstate = (unsigned int*)(zarea + n);
    int* offs = (int*)alloc((size_t)(n + 1) * 4);
    int* pos = (int*)alloc((size_t)E * 4);
    int* csr = (int*)alloc((size_t)P * 4);

    // CSR build: memset covers deg + scan-state in one call
    hipMemsetAsync(zarea, 0, (size_t)(n + NB) * 4, stream);
    k_hist<<<(E + 255) / 256, 256, 0, stream>>>(dst, deg, pos, E);
    k_scan<<<NB, 256, 0, stream>>>(deg, sstate, offs, n, P);
    k_scatter<<<SB + 272, 256, 0, stream>>>(src, dst, pos, offs, csr,
                                            W1, W2, W1t, W2t, E, n, SB);

    // layer 1 (gemm1 fuses attention logits)
    k_gemm1<<<dim3((n + 127) / 128, 2), 256, 0, stream>>>(x, W1t, asrc1, adst1, h1b, als1, ald1, n);
    k_agg1<<<(n + 3) / 4, 256, 0, stream>>>(csr, offs, als1, ald1, h1b, b1, x2b, n);

    // layer 2
    k_gemm2<<<(n + 63) / 64, 256, 0, stream>>>(x2b, W2t, asrc2, adst2, h2b, als2, ald2, n);
    k_agg2<<<(n + 3) / 4, 256, 0, stream>>>(csr, offs, als2, ald2, h2b, b2, out, n);
}

// Round 9
// 278.678 us; speedup vs baseline: 1.4585x; 1.0198x over previous
//
#include <hip/hip_runtime.h>
#include <hip/hip_bf16.h>

// GATNet v16: overlap + de-redundancy. v15 proved launch overhead ~0.7us/
// dispatch; the ~210us outside agg1 is kernel-body time. Changes:
//  - k_scatter merged INTO k_gemm1's dispatch (independent work; gemm1
//    blocks first, scatter blocks fill idle CUs -> scatter body hidden).
//  - prepw moved into k_hist's dispatch (W1t ready before gemm1).
//  - k_agg2 rewritten: 32-edge batch, lanes 0-31 compute (u,w) once per
//    edge (1 exp, was 4), inner loop gets (u,w) via __shfl broadcast.
//  - k_agg1 untouched: at random-gather service roofline (~68us, 5
//    structures all equal).

#define LRELU(x) ((x) > 0.f ? (x) : 0.2f * (x))

typedef __attribute__((ext_vector_type(8))) short short8;
typedef __attribute__((ext_vector_type(8))) unsigned short ushort8;
typedef __attribute__((ext_vector_type(4))) float f32x4;

__device__ inline unsigned short f2b(float f) {
    __hip_bfloat16 h = __float2bfloat16(f);
    return *reinterpret_cast<unsigned short*>(&h);
}
__device__ inline float b2f(unsigned short u) {
    __hip_bfloat16 h;
    *reinterpret_cast<unsigned short*>(&h) = u;
    return __bfloat162float(h);
}
__device__ inline float bl(unsigned int u) { return __uint_as_float(u << 16); }
__device__ inline float bh(unsigned int u) { return __uint_as_float(u & 0xffff0000u); }

// ---------------- hist (+ weight prep, independent) ----------------

__global__ __launch_bounds__(256) void k_hist(const int* __restrict__ dst, int* deg,
                                              int* __restrict__ pos, int E,
                                              const float* __restrict__ W1,
                                              const float* __restrict__ W2,
                                              unsigned short* __restrict__ W1t,
                                              unsigned short* __restrict__ W2t, int HB) {
    int b = blockIdx.x;
    if (b < HB) {
        int i = b * 256 + threadIdx.x;
        if (i < E) pos[i] = atomicAdd(&deg[dst[i]], 1);
    } else {
        int bb = b - HB;
        if (bb < 256) {
            int k = bb, nn = threadIdx.x;
            W1t[nn * 256 + k] = f2b(W1[k * 256 + nn]);
        } else {
            int nn = bb - 256, k = threadIdx.x;
            W2t[nn * 256 + k] = f2b(W2[k * 16 + nn]);
        }
    }
}

// ---------------- fused single-kernel scan (v15, verified) ----------------

__global__ __launch_bounds__(256) void k_scan(const int* __restrict__ deg,
                                              unsigned int* __restrict__ state,
                                              int* __restrict__ offs, int n, int P) {
    __shared__ int sc[256];
    __shared__ int sa[256];
    int b = blockIdx.x, t = threadIdx.x;
    int i = b * 256 + t;
    int v = (i < n) ? deg[i] + 1 : 0;   // +1: self loop
    sc[t] = v;
    __syncthreads();
    for (int off = 1; off < 256; off <<= 1) {
        int x = 0;
        if (t >= off) x = sc[t - off];
        __syncthreads();
        sc[t] += x;
        __syncthreads();
    }
    if (t == 255) {
        unsigned int pack = 0x80000000u | (unsigned int)sc[255];
        atomicExch(&state[b], pack);   // device-scope publish (flag+value, one word)
    }
    if (t < b) {
        unsigned int s;
        do {
            s = atomicAdd(&state[t], 0u);
        } while (!(s & 0x80000000u));
        sa[t] = (int)(s & 0x7fffffffu);
    } else {
        sa[t] = 0;
    }
    __syncthreads();
    for (int off = 128; off; off >>= 1) {
        if (t < off) sa[t] += sa[t + off];
        __syncthreads();
    }
    int prefix = sa[0];
    if (i < n) offs[i] = prefix + sc[t] - v;   // exclusive
    if (i == 0) offs[n] = P;
}

// ---------------- GEMM1 (+al1 fused) MERGED with scatter ------------------
// Blocks [0, GB): gemm1 128x128 tile; blocks [GB, GB+SB): atomic-free
// scatter. Independent work, one dispatch -> scatter hides under gemm1.

__global__ __launch_bounds__(256) void k_gemm1sc(const float* __restrict__ A,
                                                 const unsigned short* __restrict__ Wt,
                                                 const float* __restrict__ asrc,
                                                 const float* __restrict__ adst,
                                                 unsigned short* __restrict__ h1b,
                                                 float* __restrict__ als,
                                                 float* __restrict__ ald, int M,
                                                 const int* __restrict__ src,
                                                 const int* __restrict__ dst,
                                                 const int* __restrict__ pos,
                                                 const int* __restrict__ offs,
                                                 int* __restrict__ csr,
                                                 int E, int GB, int GX) {
    __shared__ unsigned short As[128][40];
    __shared__ unsigned short Bs[128][40];
    int b = blockIdx.x;
    if (b >= GB) {
        // ---- scatter branch ----
        int i = (b - GB) * 256 + threadIdx.x;
        if (i < E) {
            int d = dst[i];
            csr[offs[d] + pos[i]] = src[i];
        } else if (i < E + M) {
            int v = i - E;
            csr[offs[v + 1] - 1] = v;   // self loop in last slot of row v
        }
        return;
    }
    // ---- gemm1 branch ----
    int t = threadIdx.x;
    int bx = b % GX, by = b / GX;
    int r0 = bx * 128, c0 = by * 128;
    int srow = t >> 1, shalf = t & 1;
    int lane = t & 63, w = t >> 6;
    int lane15 = lane & 15, quad = lane >> 4;
    int rbw = (w & 1) * 64, cbw = (w >> 1) * 64;

    f32x4 acc[4][4];
#pragma unroll
    for (int i = 0; i < 4; i++)
#pragma unroll
        for (int j = 0; j < 4; j++) acc[i][j] = (f32x4)0.f;

    for (int k0 = 0; k0 < 256; k0 += 32) {
        {
            int row = r0 + srow;
            ushort8 p0, p1;
            if (row < M) {
                const float4* sp = (const float4*)&A[(size_t)row * 256 + k0 + shalf * 16];
                float4 f0 = sp[0], f1 = sp[1], f2 = sp[2], f3 = sp[3];
                p0[0] = f2b(f0.x); p0[1] = f2b(f0.y); p0[2] = f2b(f0.z); p0[3] = f2b(f0.w);
                p0[4] = f2b(f1.x); p0[5] = f2b(f1.y); p0[6] = f2b(f1.z); p0[7] = f2b(f1.w);
                p1[0] = f2b(f2.x); p1[1] = f2b(f2.y); p1[2] = f2b(f2.z); p1[3] = f2b(f2.w);
                p1[4] = f2b(f3.x); p1[5] = f2b(f3.y); p1[6] = f2b(f3.z); p1[7] = f2b(f3.w);
            } else {
                p0 = (ushort8)0; p1 = (ushort8)0;
            }
            *(ushort8*)&As[srow][shalf * 16] = p0;
            *(ushort8*)&As[srow][shalf * 16 + 8] = p1;
            const ushort8* bp = (const ushort8*)&Wt[(size_t)(c0 + srow) * 256 + k0 + shalf * 16];
            *(ushort8*)&Bs[srow][shalf * 16] = bp[0];
            *(ushort8*)&Bs[srow][shalf * 16 + 8] = bp[1];
        }
        __syncthreads();
        short8 af[4], bf[4];
#pragma unroll
        for (int i = 0; i < 4; i++)
            af[i] = *(const short8*)&As[rbw + i * 16 + lane15][quad * 8];
#pragma unroll
        for (int j = 0; j < 4; j++)
            bf[j] = *(const short8*)&Bs[cbw + j * 16 + lane15][quad * 8];
#pragma unroll
        for (int i = 0; i < 4; i++)
#pragma unroll
            for (int j = 0; j < 4; j++)
                acc[i][j] = __builtin_amdgcn_mfma_f32_16x16x32_bf16(af[i], bf[j], acc[i][j], 0, 0, 0);
        __syncthreads();
    }
    // h1b store
#pragma unroll
    for (int i = 0; i < 4; i++) {
        int rowb = r0 + rbw + i * 16 + quad * 4;
#pragma unroll
        for (int j = 0; j < 4; j++) {
            int col = c0 + cbw + j * 16 + lane15;
#pragma unroll
            for (int r = 0; r < 4; r++) {
                int row = rowb + r;
                if (row < M) h1b[(size_t)row * 256 + col] = f2b(acc[i][j][r]);
            }
        }
    }
    // fused attention logits: 2 heads per wave-col-span
    float asv[4], adv[4];
#pragma unroll
    for (int j = 0; j < 4; j++) {
        asv[j] = asrc[c0 + cbw + j * 16 + lane15];
        adv[j] = adst[c0 + cbw + j * 16 + lane15];
    }
    int hbase = (c0 + cbw) >> 5;
#pragma unroll
    for (int i = 0; i < 4; i++) {
#pragma unroll
        for (int r = 0; r < 4; r++) {
            int row = r0 + rbw + i * 16 + quad * 4 + r;
            float ps0 = acc[i][0][r] * asv[0] + acc[i][1][r] * asv[1];
            float pd0 = acc[i][0][r] * adv[0] + acc[i][1][r] * adv[1];
            float ps1 = acc[i][2][r] * asv[2] + acc[i][3][r] * asv[3];
            float pd1 = acc[i][2][r] * adv[2] + acc[i][3][r] * adv[3];
#pragma unroll
            for (int off = 1; off < 16; off <<= 1) {
                ps0 += __shfl_xor(ps0, off, 16);
                pd0 += __shfl_xor(pd0, off, 16);
                ps1 += __shfl_xor(ps1, off, 16);
                pd1 += __shfl_xor(pd1, off, 16);
            }
            if (lane15 == 0 && row < M) {
                als[(size_t)row * 8 + hbase] = ps0;
                ald[(size_t)row * 8 + hbase] = pd0;
                als[(size_t)row * 8 + hbase + 1] = ps1;
                ald[(size_t)row * 8 + hbase + 1] = pd1;
            }
        }
    }
}

// ---------------- layer-1 aggregate: self-service weights (roofline) --------

__global__ __launch_bounds__(256) void k_agg1(const int* __restrict__ csr,
                                              const int* __restrict__ offs,
                                              const float* __restrict__ als,
                                              const float* __restrict__ aldg,
                                              const unsigned short* __restrict__ h1b,
                                              const float* __restrict__ b1,
                                              unsigned short* __restrict__ x2b, int n) {
    int wid = threadIdx.x >> 6;
    int v = blockIdx.x * 4 + wid;
    if (v >= n) return;
    int lane = threadIdx.x & 63;
    int h = lane >> 3;
    int start = __builtin_amdgcn_readfirstlane(offs[v]);
    int deg = __builtin_amdgcn_readfirstlane(offs[v + 1]) - start;
    const int* __restrict__ cp = csr + start;
    int dm1 = deg - 1;
    float aldvh = aldg[(size_t)v * 8 + h];
    float a0 = 0.f, a1 = 0.f, a2 = 0.f, a3 = 0.f, wsum = 0.f;
    for (int e = 0; e < deg; e += 4) {
        int u0 = cp[e];                  // e < deg always
        int u1 = cp[min(e + 1, dm1)];
        int u2 = cp[min(e + 2, dm1)];
        int u3 = cp[min(e + 3, dm1)];
        uint2 p0 = ((const uint2*)(h1b + (size_t)u0 * 256))[lane];
        uint2 p1 = ((const uint2*)(h1b + (size_t)u1 * 256))[lane];
        uint2 p2 = ((const uint2*)(h1b + (size_t)u2 * 256))[lane];
        uint2 p3 = ((const uint2*)(h1b + (size_t)u3 * 256))[lane];
        float x0 = als[u0 * 8 + h];
        float x1 = als[u1 * 8 + h];
        float x2 = als[u2 * 8 + h];
        float x3 = als[u3 * 8 + h];
        float w0 = __expf(LRELU(x0 + aldvh));
        float w1 = __expf(LRELU(x1 + aldvh));
        float w2 = __expf(LRELU(x2 + aldvh));
        float w3 = __expf(LRELU(x3 + aldvh));
        if (e + 1 > dm1) w1 = 0.f;
        if (e + 2 > dm1) w2 = 0.f;
        if (e + 3 > dm1) w3 = 0.f;
        a0 += w0 * bl(p0.x); a1 += w0 * bh(p0.x);
        a2 += w0 * bl(p0.y); a3 += w0 * bh(p0.y);
        a0 += w1 * bl(p1.x); a1 += w1 * bh(p1.x);
        a2 += w1 * bl(p1.y); a3 += w1 * bh(p1.y);
        a0 += w2 * bl(p2.x); a1 += w2 * bh(p2.x);
        a2 += w2 * bl(p2.y); a3 += w2 * bh(p2.y);
        a0 += w3 * bl(p3.x); a1 += w3 * bh(p3.x);
        a2 += w3 * bl(p3.y); a3 += w3 * bh(p3.y);
        wsum += (w0 + w1) + (w2 + w3);
    }
    float inv = 1.0f / wsum;
    float4 bb = ((const float4*)b1)[lane];
    float o0 = fmaxf(a0 * inv + bb.x, 0.f);
    float o1 = fmaxf(a1 * inv + bb.y, 0.f);
    float o2 = fmaxf(a2 * inv + bb.z, 0.f);
    float o3 = fmaxf(a3 * inv + bb.w, 0.f);
    uint2 o;
    o.x = (unsigned int)f2b(o0) | ((unsigned int)f2b(o1) << 16);
    o.y = (unsigned int)f2b(o2) | ((unsigned int)f2b(o3) << 16);
    ((uint2*)(x2b + (size_t)v * 256))[lane] = o;
}

// ---------------- GEMM2 (MFMA) + fused layer-2 logits ----------------------

__global__ __launch_bounds__(256) void k_gemm2(const unsigned short* __restrict__ Xb,
                                               const unsigned short* __restrict__ W2t,
                                               const float* __restrict__ asrc,
                                               const float* __restrict__ adst,
                                               unsigned short* __restrict__ h2b,
                                               float* __restrict__ als,
                                               float* __restrict__ ald, int n) {
    int t = threadIdx.x;
    int lane = t & 63, w = t >> 6;
    int lane15 = lane & 15, quad = lane >> 4;
    int row0 = blockIdx.x * 64 + w * 16;
    f32x4 acc = (f32x4)0.f;
#pragma unroll
    for (int k0 = 0; k0 < 256; k0 += 32) {
        short8 a = *(const short8*)&Xb[(size_t)(row0 + lane15) * 256 + k0 + quad * 8];
        short8 b = *(const short8*)&W2t[lane15 * 256 + k0 + quad * 8];
        acc = __builtin_amdgcn_mfma_f32_16x16x32_bf16(a, b, acc, 0, 0, 0);
    }
    float asv = asrc[lane15], adv = adst[lane15];
#pragma unroll
    for (int r = 0; r < 4; r++) {
        int row = row0 + quad * 4 + r;
        float hv = acc[r];
        float ps = hv * asv, pd = hv * adv;
#pragma unroll
        for (int off = 1; off < 16; off <<= 1) {
            ps += __shfl_xor(ps, off, 16);
            pd += __shfl_xor(pd, off, 16);
        }
        if (row < n) {
            h2b[(size_t)row * 16 + lane15] = f2b(hv);
            if (lane15 == 0) {
                als[row] = ps;
                ald[row] = pd;
            }
        }
    }
}

// ---------------- layer-2 aggregate: shfl-broadcast weights -----------------
// Wave per node. slot = lane&15, cq = lane>>4 (4 cols each). Per 32-edge
// batch: lanes 0-31 (mirrored in 32-63) compute (u,w) once per edge; inner
// 2x16 groups read (u,w) via __shfl. 1 exp/edge (was 4), no LDS.

__global__ __launch_bounds__(256) void k_agg2(const int* __restrict__ csr,
                                              const int* __restrict__ offs,
                                              const float* __restrict__ als,
                                              const float* __restrict__ aldg,
                                              const unsigned short* __restrict__ h2b,
                                              const float* __restrict__ b2,
                                              float* __restrict__ out, int n) {
    int wid = threadIdx.x >> 6;
    int v = blockIdx.x * 4 + wid;
    if (v >= n) return;
    int lane = threadIdx.x & 63;
    int slot = lane & 15, cq = lane >> 4;
    int start = __builtin_amdgcn_readfirstlane(offs[v]);
    int deg = __builtin_amdgcn_readfirstlane(offs[v + 1]) - start;
    int dm1 = deg - 1;
    float aldv = aldg[v];
    float a0 = 0.f, a1 = 0.f, a2 = 0.f, a3 = 0.f, wsum = 0.f;
    for (int e = 0; e < deg; e += 32) {
        int l32 = lane & 31;
        int idx = min(e + l32, dm1);
        int uu = csr[start + idx];
        float ww = __expf(LRELU(als[uu] + aldv));
        if (e + l32 > dm1) ww = 0.f;
#pragma unroll
        for (int k = 0; k < 2; k++) {
            int sl = k * 16 + slot;
            int ue = __shfl(uu, sl, 64);
            float we = __shfl(ww, sl, 64);
            uint2 pk = ((const uint2*)(h2b + (size_t)ue * 16))[cq];
            a0 += we * bl(pk.x);
            a1 += we * bh(pk.x);
            a2 += we * bl(pk.y);
            a3 += we * bh(pk.y);
            wsum += we;
        }
    }
    // reduce over slot bits (0..3)
#pragma unroll
    for (int off = 1; off < 16; off <<= 1) {
        a0 += __shfl_xor(a0, off, 64);
        a1 += __shfl_xor(a1, off, 64);
        a2 += __shfl_xor(a2, off, 64);
        a3 += __shfl_xor(a3, off, 64);
        wsum += __shfl_xor(wsum, off, 64);
    }
    float inv = 1.0f / wsum;
    float4 bb = ((const float4*)b2)[cq];
    float o0 = a0 * inv + bb.x;
    float o1 = a1 * inv + bb.y;
    float o2 = a2 * inv + bb.z;
    float o3 = a3 * inv + bb.w;
    // log_softmax over 16 cols held as 4 cq-lanes x 4 cols (lane bits 4,5)
    float mx = fmaxf(fmaxf(o0, o1), fmaxf(o2, o3));
    mx = fmaxf(mx, __shfl_xor(mx, 16, 64));
    mx = fmaxf(mx, __shfl_xor(mx, 32, 64));
    float s = __expf(o0 - mx) + __expf(o1 - mx) + __expf(o2 - mx) + __expf(o3 - mx);
    s += __shfl_xor(s, 16, 64);
    s += __shfl_xor(s, 32, 64);
    float l = mx + __logf(s);
    if (slot == 0) {
        float4 r;
        r.x = o0 - l;
        r.y = o1 - l;
        r.z = o2 - l;
        r.w = o3 - l;
        ((float4*)out)[(size_t)v * 4 + cq] = r;
    }
}

// ---------------- launch ----------------

extern "C" void kernel_launch(void* const* d_in, const int* in_sizes, int n_in,
                              void* d_out, int out_size, void* d_ws, size_t ws_size,
                              hipStream_t stream) {
    const float* x = (const float*)d_in[0];
    const int* ei = (const int*)d_in[1];
    const float* W1 = (const float*)d_in[2];
    const float* asrc1 = (const float*)d_in[3];
    const float* adst1 = (const float*)d_in[4];
    const float* b1 = (const float*)d_in[5];
    const float* W2 = (const float*)d_in[6];
    const float* asrc2 = (const float*)d_in[7];
    const float* adst2 = (const float*)d_in[8];
    const float* b2 = (const float*)d_in[9];
    float* out = (float*)d_out;

    int n = in_sizes[0] / 256;   // 50000
    int E = in_sizes[1] / 2;     // 800000
    int P = E + n;
    const int* src = ei;
    const int* dst = ei + E;
    int NB = (n + 255) / 256;
    int HB = (E + 255) / 256;    // hist blocks
    int SB = (P + 255) / 256;    // scatter blocks
    int GX = (n + 127) / 128;    // gemm1 grid x
    int GB = GX * 2;             // gemm1 blocks

    char* p = (char*)d_ws;
    auto alloc = [&](size_t bytes) {
        void* r = (void*)p;
        p += (bytes + 255) & ~(size_t)255;
        return r;
    };
    unsigned short* h1b = (unsigned short*)alloc((size_t)n * 256 * 2);
    unsigned short* x2b = (unsigned short*)alloc((size_t)n * 256 * 2);
    unsigned short* W1t = (unsigned short*)alloc((size_t)256 * 256 * 2);
    unsigned short* W2t = (unsigned short*)alloc((size_t)16 * 256 * 2);
    float* als1 = (float*)alloc((size_t)n * 8 * 4);
    float* ald1 = (float*)alloc((size_t)n * 8 * 4);
    unsigned short* h2b = (unsigned short*)alloc((size_t)n * 16 * 2);
    float* als2 = (float*)alloc((size_t)n * 4);
    float* ald2 = (float*)alloc((size_t)n * 4);
    int* zarea = (int*)alloc((size_t)(n + NB) * 4);   // deg[n] + scan state[NB]
    int* deg = zarea;
    unsigned int* sstate = (unsigned int*)(zarea + n);
    int* offs = (int*)alloc((size_t)(n + 1) * 4);
    int* pos = (int*)alloc((size_t)E * 4);
    int* csr = (int*)alloc((size_t)P * 4);

    // CSR build + weight prep (prepw rides in hist's dispatch)
    hipMemsetAsync(zarea, 0, (size_t)(n + NB) * 4, stream);
    k_hist<<<HB + 272, 256, 0, stream>>>(dst, deg, pos, E, W1, W2, W1t, W2t, HB);
    k_scan<<<NB, 256, 0, stream>>>(deg, sstate, offs, n, P);

    // layer 1: gemm1 (+fused al1) merged with scatter in one dispatch
    k_gemm1sc<<<GB + SB, 256, 0, stream>>>(x, W1t, asrc1, adst1, h1b, als1, ald1, n,
                                           src, dst, pos, offs, csr, E, GB, GX);
    k_agg1<<<(n + 3) / 4, 256, 0, stream>>>(csr, offs, als1, ald1, h1b, b1, x2b, n);

    // layer 2
    k_gemm2<<<(n + 63) / 64, 256, 0, stream>>>(x2b, W2t, asrc2, adst2, h2b, als2, ald2, n);
    k_agg2<<<(n + 3) / 4, 256, 0, stream>>>(csr, offs, als2, ald2, h2b, b2, out, n);
}

// Round 10
// 274.395 us; speedup vs baseline: 1.4812x; 1.0156x over previous
//
#include <hip/hip_runtime.h>
#include <hip/hip_bf16.h>

// GATNet v17: visibility + hist overlap. v16's accounting has ~115us of
// unexplained time in dispatches hidden below the top-5 cutoff (=agg1's
// 67us). Changes:
//  - k_agg1 split into two half-grids (~34us each) -> top-5 cutoff drops,
//    exposing the three largest hidden kernels next round.
//  - k_hist merged into k_gemm1's dispatch (independent work; 800k atomic
//    latency hides under MFMA). prepw is its own tiny leading dispatch.
//  - scatter standalone again (needs scan output).

#define LRELU(x) ((x) > 0.f ? (x) : 0.2f * (x))

typedef __attribute__((ext_vector_type(8))) short short8;
typedef __attribute__((ext_vector_type(8))) unsigned short ushort8;
typedef __attribute__((ext_vector_type(4))) float f32x4;

__device__ inline unsigned short f2b(float f) {
    __hip_bfloat16 h = __float2bfloat16(f);
    return *reinterpret_cast<unsigned short*>(&h);
}
__device__ inline float b2f(unsigned short u) {
    __hip_bfloat16 h;
    *reinterpret_cast<unsigned short*>(&h) = u;
    return __bfloat162float(h);
}
__device__ inline float bl(unsigned int u) { return __uint_as_float(u << 16); }
__device__ inline float bh(unsigned int u) { return __uint_as_float(u & 0xffff0000u); }

// ---------------- weight prep (standalone, tiny, must precede gemm1) -------

__global__ __launch_bounds__(256) void k_prep(const float* __restrict__ W1,
                                              const float* __restrict__ W2,
                                              unsigned short* __restrict__ W1t,
                                              unsigned short* __restrict__ W2t) {
    int b = blockIdx.x;
    if (b < 256) {
        int k = b, nn = threadIdx.x;
        W1t[nn * 256 + k] = f2b(W1[k * 256 + nn]);
    } else {
        int nn = b - 256, k = threadIdx.x;
        W2t[nn * 256 + k] = f2b(W2[k * 16 + nn]);
    }
}

// ---------------- fused single-kernel scan (v15, verified) ----------------

__global__ __launch_bounds__(256) void k_scan(const int* __restrict__ deg,
                                              unsigned int* __restrict__ state,
                                              int* __restrict__ offs, int n, int P) {
    __shared__ int sc[256];
    __shared__ int sa[256];
    int b = blockIdx.x, t = threadIdx.x;
    int i = b * 256 + t;
    int v = (i < n) ? deg[i] + 1 : 0;   // +1: self loop
    sc[t] = v;
    __syncthreads();
    for (int off = 1; off < 256; off <<= 1) {
        int x = 0;
        if (t >= off) x = sc[t - off];
        __syncthreads();
        sc[t] += x;
        __syncthreads();
    }
    if (t == 255) {
        unsigned int pack = 0x80000000u | (unsigned int)sc[255];
        atomicExch(&state[b], pack);   // device-scope publish (flag+value, one word)
    }
    if (t < b) {
        unsigned int s;
        do {
            s = atomicAdd(&state[t], 0u);
        } while (!(s & 0x80000000u));
        sa[t] = (int)(s & 0x7fffffffu);
    } else {
        sa[t] = 0;
    }
    __syncthreads();
    for (int off = 128; off; off >>= 1) {
        if (t < off) sa[t] += sa[t + off];
        __syncthreads();
    }
    int prefix = sa[0];
    if (i < n) offs[i] = prefix + sc[t] - v;   // exclusive
    if (i == 0) offs[n] = P;
}

// ---------------- scatter (atomic-free via pos) ----------------

__global__ void k_scatter(const int* __restrict__ src, const int* __restrict__ dst,
                          const int* __restrict__ pos, const int* __restrict__ offs,
                          int* __restrict__ csr, int E, int n) {
    int i = blockIdx.x * blockDim.x + threadIdx.x;
    if (i < E) {
        int d = dst[i];
        csr[offs[d] + pos[i]] = src[i];
    } else if (i < E + n) {
        int v = i - E;
        csr[offs[v + 1] - 1] = v;   // self loop in the last slot of row v
    }
}

// ---------------- GEMM1 (+al1 fused) MERGED with hist ---------------------
// Blocks [0, GB): gemm1 128x128 tile (+fused logits). Blocks [GB, GB+HB):
// hist (atomic deg/pos). Independent work -> atomic latency hides under MFMA.

__global__ __launch_bounds__(256) void k_gemm1h(const float* __restrict__ A,
                                                const unsigned short* __restrict__ Wt,
                                                const float* __restrict__ asrc,
                                                const float* __restrict__ adst,
                                                unsigned short* __restrict__ h1b,
                                                float* __restrict__ als,
                                                float* __restrict__ ald, int M,
                                                const int* __restrict__ dst,
                                                int* deg, int* __restrict__ pos,
                                                int E, int GB, int GX) {
    __shared__ unsigned short As[128][40];
    __shared__ unsigned short Bs[128][40];
    int b = blockIdx.x;
    if (b >= GB) {
        // ---- hist branch ----
        int i = (b - GB) * 256 + threadIdx.x;
        if (i < E) pos[i] = atomicAdd(&deg[dst[i]], 1);
        return;
    }
    // ---- gemm1 branch ----
    int t = threadIdx.x;
    int bx = b % GX, by = b / GX;
    int r0 = bx * 128, c0 = by * 128;
    int srow = t >> 1, shalf = t & 1;
    int lane = t & 63, w = t >> 6;
    int lane15 = lane & 15, quad = lane >> 4;
    int rbw = (w & 1) * 64, cbw = (w >> 1) * 64;

    f32x4 acc[4][4];
#pragma unroll
    for (int i = 0; i < 4; i++)
#pragma unroll
        for (int j = 0; j < 4; j++) acc[i][j] = (f32x4)0.f;

    for (int k0 = 0; k0 < 256; k0 += 32) {
        {
            int row = r0 + srow;
            ushort8 p0, p1;
            if (row < M) {
                const float4* sp = (const float4*)&A[(size_t)row * 256 + k0 + shalf * 16];
                float4 f0 = sp[0], f1 = sp[1], f2 = sp[2], f3 = sp[3];
                p0[0] = f2b(f0.x); p0[1] = f2b(f0.y); p0[2] = f2b(f0.z); p0[3] = f2b(f0.w);
                p0[4] = f2b(f1.x); p0[5] = f2b(f1.y); p0[6] = f2b(f1.z); p0[7] = f2b(f1.w);
                p1[0] = f2b(f2.x); p1[1] = f2b(f2.y); p1[2] = f2b(f2.z); p1[3] = f2b(f2.w);
                p1[4] = f2b(f3.x); p1[5] = f2b(f3.y); p1[6] = f2b(f3.z); p1[7] = f2b(f3.w);
            } else {
                p0 = (ushort8)0; p1 = (ushort8)0;
            }
            *(ushort8*)&As[srow][shalf * 16] = p0;
            *(ushort8*)&As[srow][shalf * 16 + 8] = p1;
            const ushort8* bp = (const ushort8*)&Wt[(size_t)(c0 + srow) * 256 + k0 + shalf * 16];
            *(ushort8*)&Bs[srow][shalf * 16] = bp[0];
            *(ushort8*)&Bs[srow][shalf * 16 + 8] = bp[1];
        }
        __syncthreads();
        short8 af[4], bf[4];
#pragma unroll
        for (int i = 0; i < 4; i++)
            af[i] = *(const short8*)&As[rbw + i * 16 + lane15][quad * 8];
#pragma unroll
        for (int j = 0; j < 4; j++)
            bf[j] = *(const short8*)&Bs[cbw + j * 16 + lane15][quad * 8];
#pragma unroll
        for (int i = 0; i < 4; i++)
#pragma unroll
            for (int j = 0; j < 4; j++)
                acc[i][j] = __builtin_amdgcn_mfma_f32_16x16x32_bf16(af[i], bf[j], acc[i][j], 0, 0, 0);
        __syncthreads();
    }
    // h1b store
#pragma unroll
    for (int i = 0; i < 4; i++) {
        int rowb = r0 + rbw + i * 16 + quad * 4;
#pragma unroll
        for (int j = 0; j < 4; j++) {
            int col = c0 + cbw + j * 16 + lane15;
#pragma unroll
            for (int r = 0; r < 4; r++) {
                int row = rowb + r;
                if (row < M) h1b[(size_t)row * 256 + col] = f2b(acc[i][j][r]);
            }
        }
    }
    // fused attention logits: 2 heads per wave-col-span
    float asv[4], adv[4];
#pragma unroll
    for (int j = 0; j < 4; j++) {
        asv[j] = asrc[c0 + cbw + j * 16 + lane15];
        adv[j] = adst[c0 + cbw + j * 16 + lane15];
    }
    int hbase = (c0 + cbw) >> 5;
#pragma unroll
    for (int i = 0; i < 4; i++) {
#pragma unroll
        for (int r = 0; r < 4; r++) {
            int row = r0 + rbw + i * 16 + quad * 4 + r;
            float ps0 = acc[i][0][r] * asv[0] + acc[i][1][r] * asv[1];
            float pd0 = acc[i][0][r] * adv[0] + acc[i][1][r] * adv[1];
            float ps1 = acc[i][2][r] * asv[2] + acc[i][3][r] * asv[3];
            float pd1 = acc[i][2][r] * adv[2] + acc[i][3][r] * adv[3];
#pragma unroll
            for (int off = 1; off < 16; off <<= 1) {
                ps0 += __shfl_xor(ps0, off, 16);
                pd0 += __shfl_xor(pd0, off, 16);
                ps1 += __shfl_xor(ps1, off, 16);
                pd1 += __shfl_xor(pd1, off, 16);
            }
            if (lane15 == 0 && row < M) {
                als[(size_t)row * 8 + hbase] = ps0;
                ald[(size_t)row * 8 + hbase] = pd0;
                als[(size_t)row * 8 + hbase + 1] = ps1;
                ald[(size_t)row * 8 + hbase + 1] = pd1;
            }
        }
    }
}

// ---------------- layer-1 aggregate: self-service weights (roofline) --------
// Split into two half-grid dispatches (v0 offset) for top-5 visibility.

__global__ __launch_bounds__(256) void k_agg1(const int* __restrict__ csr,
                                              const int* __restrict__ offs,
                                              const float* __restrict__ als,
                                              const float* __restrict__ aldg,
                                              const unsigned short* __restrict__ h1b,
                                              const float* __restrict__ b1,
                                              unsigned short* __restrict__ x2b,
                                              int v0, int vend) {
    int wid = threadIdx.x >> 6;
    int v = v0 + blockIdx.x * 4 + wid;
    if (v >= vend) return;
    int lane = threadIdx.x & 63;
    int h = lane >> 3;
    int start = __builtin_amdgcn_readfirstlane(offs[v]);
    int deg = __builtin_amdgcn_readfirstlane(offs[v + 1]) - start;
    const int* __restrict__ cp = csr + start;
    int dm1 = deg - 1;
    float aldvh = aldg[(size_t)v * 8 + h];
    float a0 = 0.f, a1 = 0.f, a2 = 0.f, a3 = 0.f, wsum = 0.f;
    for (int e = 0; e < deg; e += 4) {
        int u0 = cp[e];                  // e < deg always
        int u1 = cp[min(e + 1, dm1)];
        int u2 = cp[min(e + 2, dm1)];
        int u3 = cp[min(e + 3, dm1)];
        uint2 p0 = ((const uint2*)(h1b + (size_t)u0 * 256))[lane];
        uint2 p1 = ((const uint2*)(h1b + (size_t)u1 * 256))[lane];
        uint2 p2 = ((const uint2*)(h1b + (size_t)u2 * 256))[lane];
        uint2 p3 = ((const uint2*)(h1b + (size_t)u3 * 256))[lane];
        float x0 = als[u0 * 8 + h];
        float x1 = als[u1 * 8 + h];
        float x2 = als[u2 * 8 + h];
        float x3 = als[u3 * 8 + h];
        float w0 = __expf(LRELU(x0 + aldvh));
        float w1 = __expf(LRELU(x1 + aldvh));
        float w2 = __expf(LRELU(x2 + aldvh));
        float w3 = __expf(LRELU(x3 + aldvh));
        if (e + 1 > dm1) w1 = 0.f;
        if (e + 2 > dm1) w2 = 0.f;
        if (e + 3 > dm1) w3 = 0.f;
        a0 += w0 * bl(p0.x); a1 += w0 * bh(p0.x);
        a2 += w0 * bl(p0.y); a3 += w0 * bh(p0.y);
        a0 += w1 * bl(p1.x); a1 += w1 * bh(p1.x);
        a2 += w1 * bl(p1.y); a3 += w1 * bh(p1.y);
        a0 += w2 * bl(p2.x); a1 += w2 * bh(p2.x);
        a2 += w2 * bl(p2.y); a3 += w2 * bh(p2.y);
        a0 += w3 * bl(p3.x); a1 += w3 * bh(p3.x);
        a2 += w3 * bl(p3.y); a3 += w3 * bh(p3.y);
        wsum += (w0 + w1) + (w2 + w3);
    }
    float inv = 1.0f / wsum;
    float4 bb = ((const float4*)b1)[lane];
    float o0 = fmaxf(a0 * inv + bb.x, 0.f);
    float o1 = fmaxf(a1 * inv + bb.y, 0.f);
    float o2 = fmaxf(a2 * inv + bb.z, 0.f);
    float o3 = fmaxf(a3 * inv + bb.w, 0.f);
    uint2 o;
    o.x = (unsigned int)f2b(o0) | ((unsigned int)f2b(o1) << 16);
    o.y = (unsigned int)f2b(o2) | ((unsigned int)f2b(o3) << 16);
    ((uint2*)(x2b + (size_t)v * 256))[lane] = o;
}

// ---------------- GEMM2 (MFMA) + fused layer-2 logits ----------------------

__global__ __launch_bounds__(256) void k_gemm2(const unsigned short* __restrict__ Xb,
                                               const unsigned short* __restrict__ W2t,
                                               const float* __restrict__ asrc,
                                               const float* __restrict__ adst,
                                               unsigned short* __restrict__ h2b,
                                               float* __restrict__ als,
                                               float* __restrict__ ald, int n) {
    int t = threadIdx.x;
    int lane = t & 63, w = t >> 6;
    int lane15 = lane & 15, quad = lane >> 4;
    int row0 = blockIdx.x * 64 + w * 16;
    f32x4 acc = (f32x4)0.f;
#pragma unroll
    for (int k0 = 0; k0 < 256; k0 += 32) {
        short8 a = *(const short8*)&Xb[(size_t)(row0 + lane15) * 256 + k0 + quad * 8];
        short8 b = *(const short8*)&W2t[lane15 * 256 + k0 + quad * 8];
        acc = __builtin_amdgcn_mfma_f32_16x16x32_bf16(a, b, acc, 0, 0, 0);
    }
    float asv = asrc[lane15], adv = adst[lane15];
#pragma unroll
    for (int r = 0; r < 4; r++) {
        int row = row0 + quad * 4 + r;
        float hv = acc[r];
        float ps = hv * asv, pd = hv * adv;
#pragma unroll
        for (int off = 1; off < 16; off <<= 1) {
            ps += __shfl_xor(ps, off, 16);
            pd += __shfl_xor(pd, off, 16);
        }
        if (row < n) {
            h2b[(size_t)row * 16 + lane15] = f2b(hv);
            if (lane15 == 0) {
                als[row] = ps;
                ald[row] = pd;
            }
        }
    }
}

// ---------------- layer-2 aggregate: shfl-broadcast weights -----------------

__global__ __launch_bounds__(256) void k_agg2(const int* __restrict__ csr,
                                              const int* __restrict__ offs,
                                              const float* __restrict__ als,
                                              const float* __restrict__ aldg,
                                              const unsigned short* __restrict__ h2b,
                                              const float* __restrict__ b2,
                                              float* __restrict__ out, int n) {
    int wid = threadIdx.x >> 6;
    int v = blockIdx.x * 4 + wid;
    if (v >= n) return;
    int lane = threadIdx.x & 63;
    int slot = lane & 15, cq = lane >> 4;
    int start = __builtin_amdgcn_readfirstlane(offs[v]);
    int deg = __builtin_amdgcn_readfirstlane(offs[v + 1]) - start;
    int dm1 = deg - 1;
    float aldv = aldg[v];
    float a0 = 0.f, a1 = 0.f, a2 = 0.f, a3 = 0.f, wsum = 0.f;
    for (int e = 0; e < deg; e += 32) {
        int l32 = lane & 31;
        int idx = min(e + l32, dm1);
        int uu = csr[start + idx];
        float ww = __expf(LRELU(als[uu] + aldv));
        if (e + l32 > dm1) ww = 0.f;
#pragma unroll
        for (int k = 0; k < 2; k++) {
            int sl = k * 16 + slot;
            int ue = __shfl(uu, sl, 64);
            float we = __shfl(ww, sl, 64);
            uint2 pk = ((const uint2*)(h2b + (size_t)ue * 16))[cq];
            a0 += we * bl(pk.x);
            a1 += we * bh(pk.x);
            a2 += we * bl(pk.y);
            a3 += we * bh(pk.y);
            wsum += we;
        }
    }
#pragma unroll
    for (int off = 1; off < 16; off <<= 1) {
        a0 += __shfl_xor(a0, off, 64);
        a1 += __shfl_xor(a1, off, 64);
        a2 += __shfl_xor(a2, off, 64);
        a3 += __shfl_xor(a3, off, 64);
        wsum += __shfl_xor(wsum, off, 64);
    }
    float inv = 1.0f / wsum;
    float4 bb = ((const float4*)b2)[cq];
    float o0 = a0 * inv + bb.x;
    float o1 = a1 * inv + bb.y;
    float o2 = a2 * inv + bb.z;
    float o3 = a3 * inv + bb.w;
    float mx = fmaxf(fmaxf(o0, o1), fmaxf(o2, o3));
    mx = fmaxf(mx, __shfl_xor(mx, 16, 64));
    mx = fmaxf(mx, __shfl_xor(mx, 32, 64));
    float s = __expf(o0 - mx) + __expf(o1 - mx) + __expf(o2 - mx) + __expf(o3 - mx);
    s += __shfl_xor(s, 16, 64);
    s += __shfl_xor(s, 32, 64);
    float l = mx + __logf(s);
    if (slot == 0) {
        float4 r;
        r.x = o0 - l;
        r.y = o1 - l;
        r.z = o2 - l;
        r.w = o3 - l;
        ((float4*)out)[(size_t)v * 4 + cq] = r;
    }
}

// ---------------- launch ----------------

extern "C" void kernel_launch(void* const* d_in, const int* in_sizes, int n_in,
                              void* d_out, int out_size, void* d_ws, size_t ws_size,
                              hipStream_t stream) {
    const float* x = (const float*)d_in[0];
    const int* ei = (const int*)d_in[1];
    const float* W1 = (const float*)d_in[2];
    const float* asrc1 = (const float*)d_in[3];
    const float* adst1 = (const float*)d_in[4];
    const float* b1 = (const float*)d_in[5];
    const float* W2 = (const float*)d_in[6];
    const float* asrc2 = (const float*)d_in[7];
    const float* adst2 = (const float*)d_in[8];
    const float* b2 = (const float*)d_in[9];
    float* out = (float*)d_out;

    int n = in_sizes[0] / 256;   // 50000
    int E = in_sizes[1] / 2;     // 800000
    int P = E + n;
    const int* src = ei;
    const int* dst = ei + E;
    int NB = (n + 255) / 256;
    int HB = (E + 255) / 256;    // hist blocks
    int GX = (n + 127) / 128;    // gemm1 grid x
    int GB = GX * 2;             // gemm1 blocks

    char* p = (char*)d_ws;
    auto alloc = [&](size_t bytes) {
        void* r = (void*)p;
        p += (bytes + 255) & ~(size_t)255;
        return r;
    };
    unsigned short* h1b = (unsigned short*)alloc((size_t)n * 256 * 2);
    unsigned short* x2b = (unsigned short*)alloc((size_t)n * 256 * 2);
    unsigned short* W1t = (unsigned short*)alloc((size_t)256 * 256 * 2);
    unsigned short* W2t = (unsigned short*)alloc((size_t)16 * 256 * 2);
    float* als1 = (float*)alloc((size_t)n * 8 * 4);
    float* ald1 = (float*)alloc((size_t)n * 8 * 4);
    unsigned short* h2b = (unsigned short*)alloc((size_t)n * 16 * 2);
    float* als2 = (float*)alloc((size_t)n * 4);
    float* ald2 = (float*)alloc((size_t)n * 4);
    int* zarea = (int*)alloc((size_t)(n + NB) * 4);   // deg[n] + scan state[NB]
    int* deg = zarea;
    unsigned int* sstate = (unsigned int*)(zarea + n);
    int* offs = (int*)alloc((size_t)(n + 1) * 4);
    int* pos = (int*)alloc((size_t)E * 4);
    int* csr = (int*)alloc((size_t)P * 4);

    hipMemsetAsync(zarea, 0, (size_t)(n + NB) * 4, stream);
    k_prep<<<272, 256, 0, stream>>>(W1, W2, W1t, W2t);

    // gemm1 (+fused al1) merged with hist: atomics overlap MFMA
    k_gemm1h<<<GB + HB, 256, 0, stream>>>(x, W1t, asrc1, adst1, h1b, als1, ald1, n,
                                          dst, deg, pos, E, GB, GX);
    k_scan<<<NB, 256, 0, stream>>>(deg, sstate, offs, n, P);
    k_scatter<<<(P + 255) / 256, 256, 0, stream>>>(src, dst, pos, offs, csr, E, n);

    // layer-1 aggregate, split for profiling visibility
    int nh = ((n / 2) + 3) & ~3;   // 25000, multiple of 4
    k_agg1<<<(nh + 3) / 4, 256, 0, stream>>>(csr, offs, als1, ald1, h1b, b1, x2b, 0, nh);
    k_agg1<<<(n - nh + 3) / 4, 256, 0, stream>>>(csr, offs, als1, ald1, h1b, b1, x2b, nh, n);

    // layer 2
    k_gemm2<<<(n + 63) / 64, 256, 0, stream>>>(x2b, W2t, asrc2, adst2, h2b, als2, ald2, n);
    k_agg2<<<(n + 3) / 4, 256, 0, stream>>>(csr, offs, als2, ald2, h2b, b2, out, n);
}